// Round 11
// baseline (214.208 us; speedup 1.0000x reference)
//
#include <hip/hip_runtime.h>
#include <math.h>

// Problem constants (from reference setup_inputs)
#define N_ROWS 262144
#define DX 64
#define DZ 32
#define NB 1024
#define NBF 262144.0f
#define MIN_ASSIGN (0.1f / 1024.0f)
#define BIAS 512.0f

typedef short shortx8 __attribute__((ext_vector_type(8)));
typedef float floatx4 __attribute__((ext_vector_type(4)));

// ---------- fast-path workspace layout (float offsets) ----------
#define WS_VNORMB 64                       // + 1024  (‖v‖² + 512 bias)
#define WS_MUNORM 1088                     // + 1024
#define WS_WENCT  2112                     // + 1024  (32x64 bf16 W_enc^T)
#define WS_WDECB  3136                     // + 1024  (32x64 bf16 W_dec)
#define WS_VBF    4160                     // + 16384 (1024x32 bf16 v)
#define WS_VBF2   20544                    // + 16384 (1024x32 bf16 -2v)
#define WS_ZP     36928                    // + 4194304
#define WS_BIDX   4231232                  // + 131072
#define WS_SUMZC  4362304                  // + 32768
#define WS_COUNTS 4395072                  // + 1024
#define WS_PART   4396096                  // + 2162688
#define WS_FINS   6558784                  // [0]=mx,[1]=na_mx,[2]=done,[64..1088)=isd
#define WS_RPART  6559872                  // + 8192 (per-wave recon partials)
#define WS_CPART  6568064                  // + 8192
#define WS_TOTAL  6576256                  // floats (~26.3 MB)
#define PART_STRIDE 33792
#define HCHUNKS 64
#define HROWS  (N_ROWS / HCHUNKS)          // 4096
#define HROLES 17
#define HBLOCKS (HROLES * HCHUNKS)         // 1088
#define HSCALE 2048.0f
#define RF_BLOCKS 132
#define ENC_THREADS 128
#define ENC_ROWS 64                        // 64 rows/block = 32 rows/WAVE
#define ENC_BLOCKS (N_ROWS / ENC_ROWS)     // 4096 -> 16 blocks/CU = 32 waves/CU
#define ZSTR 40                            // zbf row stride (shorts)

// ---------- fallback (round-1) workspace layout ----------
#define FB_RECON  0
#define FB_COMMIT 1
#define FB_COUNTS 64
#define FB_SUMZ   1088
#define FB_VNORM  33856
#define FB_MUTAB  34880
#define FB_ZERO_N 33856

static __device__ __forceinline__ short f2bf(float f) {
    union { float f; unsigned u; } v; v.f = f;
    unsigned r = v.u + 0x7FFFu + ((v.u >> 16) & 1u);   // RNE
    return (short)(r >> 16);
}
static __device__ __forceinline__ float bits2f(unsigned u) {
    union { unsigned u; float f; } v; v.u = u; return v.f;
}
static __device__ __forceinline__ unsigned pk2(float lo, float hi) {
    unsigned a = __builtin_bit_cast(unsigned, lo) + 0x8000u;
    unsigned b = __builtin_bit_cast(unsigned, hi) + 0x8000u;
    return __builtin_amdgcn_perm(b, a, 0x07060302u);
}

__global__ __launch_bounds__(256) void zero_kernel(float* __restrict__ p, int n) {
    int i = blockIdx.x * 256 + threadIdx.x;
    if (i < n) p[i] = 0.0f;
}

// Per-bin prep (unchanged): biased vnorm, munorm, bf16 codebooks, bf16 weights.
__global__ __launch_bounds__(64) void vq_prep(
    const float* __restrict__ vectors, const float* __restrict__ W_enc,
    const float* __restrict__ W_dec, const float* __restrict__ b_dec,
    float* __restrict__ ws)
{
    const int j = blockIdx.x;
    const int t = threadIdx.x;
    float* vnormb = ws + WS_VNORMB;
    float* munorm = ws + WS_MUNORM;
    short* vbf  = (short*)(ws + WS_VBF);
    short* vbf2 = (short*)(ws + WS_VBF2);
    short* wencT = (short*)(ws + WS_WENCT);
    short* wdecb = (short*)(ws + WS_WDECB);

    if (j == 0 && t == 2) ws[WS_FINS + 2] = 0.0f;      // redfin done counter
    if (j == 0) {
        #pragma unroll
        for (int c = 0; c < DZ; ++c)
            wencT[c * DX + t] = f2bf(W_enc[t * DZ + c]);
    }
    if (j == 1) {
        #pragma unroll
        for (int c = 0; c < DZ; ++c)
            wdecb[c * DX + t] = f2bf(W_dec[c * DX + t]);
    }

    __shared__ float v[DZ];
    if (t < DZ) {
        float vv = vectors[j * DZ + t];
        v[t] = vv;
        vbf[j * DZ + t]  = f2bf(vv);
        vbf2[j * DZ + t] = f2bf(-2.0f * vv);
    }
    __syncthreads();
    float m = b_dec[t];
    #pragma unroll
    for (int k = 0; k < DZ; ++k) m = fmaf(v[k], W_dec[k * DX + t], m);
    float ms = m * m;
    #pragma unroll
    for (int off = 32; off > 0; off >>= 1) ms += __shfl_down(ms, off, 64);
    if (t == 0) {
        munorm[j] = ms;
        float s = 0.0f;
        #pragma unroll
        for (int k = 0; k < DZ; ++k) s = fmaf(v[k], v[k], s);
        vnormb[j] = s + BIAS;
    }
}

// ---------- encmin v4: 32 rows/WAVE, barrier-free, wave-private LDS ----------
// r10's encmin had a hard structural cap: 64 rows/wave -> only 4096 waves total
// = 16 waves/CU (grid-limited 50% occupancy). v4 halves rows/wave -> 8192 waves
// = 32 waves/CU, __launch_bounds__(128,8) caps VGPR at 64 to allow it.
// x staged straight into MFMA fragments from global (no xbf, no phase-A barrier);
// xnorm/x·b_dec from fp32 fragments via shfl reductions; y·v via fragment dot +
// 4-lane shfl into a tiny sdot[]. ALL LDS is wave-private -> zero barriers.
__global__ __launch_bounds__(ENC_THREADS, 8) void vq_encmin(
    const float* __restrict__ x, const short* __restrict__ wencT,
    const float* __restrict__ b_enc, const short* __restrict__ wdecb,
    const float* __restrict__ b_dec, const short* __restrict__ vbf,
    const short* __restrict__ vbf2, const float* __restrict__ vnormb,
    const float* __restrict__ munorm,
    unsigned* __restrict__ zp, unsigned short* __restrict__ bidx_out,
    float* __restrict__ rpart, float* __restrict__ cpart)
{
    __shared__ __attribute__((aligned(16))) short zbf[ENC_ROWS * ZSTR]; // 5120 B
    __shared__ unsigned skey[ENC_ROWS];                                 // 256 B
    __shared__ float sdot[ENC_ROWS];                                    // 256 B

    const int t = threadIdx.x;
    const int w = t >> 6, l = t & 63, lm = l & 15, lq4 = l >> 4;
    const int wrow0 = w * 32;                        // wave's first block-local row
    const int rowbase = blockIdx.x * ENC_ROWS + wrow0;  // absolute

    const float be0 = b_enc[lm], be1 = b_enc[16 + lm];
    const float4 bd0 = *(const float4*)(b_dec + lq4 * 8);
    const float4 bd1 = *(const float4*)(b_dec + lq4 * 8 + 4);
    const float4 bd2 = *(const float4*)(b_dec + 32 + lq4 * 8);
    const float4 bd3 = *(const float4*)(b_dec + 32 + lq4 * 8 + 4);

    float xnorm = 0.0f, xb = 0.0f;
    unsigned ypkv[8];

    // ---- B: per row-tile, stage x->frags, z & y MFMAs, scatter z to LDS ----
    #pragma unroll
    for (int rt = 0; rt < 2; ++rt) {
        const float* xr = x + (size_t)(rowbase + rt * 16 + lm) * DX + lq4 * 8;
        const float4 v0 = *(const float4*)(xr);
        const float4 v1 = *(const float4*)(xr + 4);
        const float4 v2 = *(const float4*)(xr + 32);
        const float4 v3 = *(const float4*)(xr + 36);

        // partial xnorm / x·b_dec over this lane's 16 cols (fp32)
        float pn = v0.x*v0.x + v0.y*v0.y + v0.z*v0.z + v0.w*v0.w
                 + v1.x*v1.x + v1.y*v1.y + v1.z*v1.z + v1.w*v1.w
                 + v2.x*v2.x + v2.y*v2.y + v2.z*v2.z + v2.w*v2.w
                 + v3.x*v3.x + v3.y*v3.y + v3.z*v3.z + v3.w*v3.w;
        float pb = v0.x*bd0.x + v0.y*bd0.y + v0.z*bd0.z + v0.w*bd0.w
                 + v1.x*bd1.x + v1.y*bd1.y + v1.z*bd1.z + v1.w*bd1.w
                 + v2.x*bd2.x + v2.y*bd2.y + v2.z*bd2.z + v2.w*bd2.w
                 + v3.x*bd3.x + v3.y*bd3.y + v3.z*bd3.z + v3.w*bd3.w;
        pn += __shfl_xor(pn, 16, 64); pn += __shfl_xor(pn, 32, 64);
        pb += __shfl_xor(pb, 16, 64); pb += __shfl_xor(pb, 32, 64);
        if (rt == lq4) { xnorm = pn; xb = pb; }      // lane's own row (l<32 valid)

        // pack to bf16 A-fragments (cols 0-31 | 32-63, this lane's lq4 slice)
        union { uint2 q[2]; shortx8 s; } ax0, ax1;
        ax0.q[0] = (uint2){pk2(v0.x, v0.y), pk2(v0.z, v0.w)};
        ax0.q[1] = (uint2){pk2(v1.x, v1.y), pk2(v1.z, v1.w)};
        ax1.q[0] = (uint2){pk2(v2.x, v2.y), pk2(v2.z, v2.w)};
        ax1.q[1] = (uint2){pk2(v3.x, v3.y), pk2(v3.z, v3.w)};

        // weights (transient, L1-hot 4KB tables)
        const shortx8 we00 = *(const shortx8*)&wencT[(0 * 16 + lm) * DX + 0 * 32 + lq4 * 8];
        const shortx8 we01 = *(const shortx8*)&wencT[(0 * 16 + lm) * DX + 1 * 32 + lq4 * 8];
        const shortx8 we10 = *(const shortx8*)&wencT[(1 * 16 + lm) * DX + 0 * 32 + lq4 * 8];
        const shortx8 we11 = *(const shortx8*)&wencT[(1 * 16 + lm) * DX + 1 * 32 + lq4 * 8];
        const shortx8 wd00 = *(const shortx8*)&wdecb[(0 * 16 + lm) * DX + 0 * 32 + lq4 * 8];
        const shortx8 wd01 = *(const shortx8*)&wdecb[(0 * 16 + lm) * DX + 1 * 32 + lq4 * 8];
        const shortx8 wd10 = *(const shortx8*)&wdecb[(1 * 16 + lm) * DX + 0 * 32 + lq4 * 8];
        const shortx8 wd11 = *(const shortx8*)&wdecb[(1 * 16 + lm) * DX + 1 * 32 + lq4 * 8];

        floatx4 z0 = {be0, be0, be0, be0}, z1 = {be1, be1, be1, be1};
        z0 = __builtin_amdgcn_mfma_f32_16x16x32_bf16(ax0.s, we00, z0, 0, 0, 0);
        z0 = __builtin_amdgcn_mfma_f32_16x16x32_bf16(ax1.s, we01, z0, 0, 0, 0);
        z1 = __builtin_amdgcn_mfma_f32_16x16x32_bf16(ax0.s, we10, z1, 0, 0, 0);
        z1 = __builtin_amdgcn_mfma_f32_16x16x32_bf16(ax1.s, we11, z1, 0, 0, 0);
        floatx4 y0 = {0.f, 0.f, 0.f, 0.f}, y1 = {0.f, 0.f, 0.f, 0.f};
        y0 = __builtin_amdgcn_mfma_f32_16x16x32_bf16(ax0.s, wd00, y0, 0, 0, 0);
        y0 = __builtin_amdgcn_mfma_f32_16x16x32_bf16(ax1.s, wd01, y0, 0, 0, 0);
        y1 = __builtin_amdgcn_mfma_f32_16x16x32_bf16(ax0.s, wd10, y1, 0, 0, 0);
        y1 = __builtin_amdgcn_mfma_f32_16x16x32_bf16(ax1.s, wd11, y1, 0, 0, 0);

        #pragma unroll
        for (int reg = 0; reg < 4; ++reg) {
            const int row = wrow0 + rt * 16 + lq4 * 4 + reg;   // wave-private
            const unsigned zpk = pk2(z0[reg], z1[reg]);
            zbf[row * ZSTR + lm]      = (short)(zpk & 0xFFFFu);
            zbf[row * ZSTR + 16 + lm] = (short)(zpk >> 16);
            ypkv[rt * 4 + reg] = pk2(y0[reg], y1[reg]);
        }
    }
    // no barrier: zbf rows written/read by the SAME wave only

    // ---- C: MFMA argmin over 1024 codes ----
    shortx8 afrag[2];
    #pragma unroll
    for (int rt = 0; rt < 2; ++rt)
        afrag[rt] = *(const shortx8*)&zbf[(wrow0 + rt * 16 + lm) * ZSTR + lq4 * 8];

    unsigned key[8];
    #pragma unroll
    for (int k = 0; k < 8; ++k) key[k] = 0xFFFFFFFFu;

    #pragma unroll 4
    for (int jt = 0; jt < 64; ++jt) {
        const int jbase = jt * 16 + lm;
        const shortx8 bfrag = *(const shortx8*)&vbf2[(size_t)jbase * DZ + lq4 * 8];
        const float vn = vnormb[jbase];
        floatx4 cin = {vn, vn, vn, vn};
        #pragma unroll
        for (int rt = 0; rt < 2; ++rt) {
            floatx4 acc = __builtin_amdgcn_mfma_f32_16x16x32_bf16(
                afrag[rt], bfrag, cin, 0, 0, 0);
            #pragma unroll
            for (int reg = 0; reg < 4; ++reg) {
                unsigned u = __builtin_bit_cast(unsigned, acc[reg]);
                unsigned pk = (u & 0xFFFFFC00u) | (unsigned)jbase;
                int k = rt * 4 + reg;
                key[k] = key[k] < pk ? key[k] : pk;
            }
        }
    }

    // cross-lane min over the 16 columns (lm bits); ties -> smaller j
    #pragma unroll
    for (int k = 0; k < 8; ++k) {
        unsigned kv = key[k];
        #pragma unroll
        for (int m = 1; m <= 8; m <<= 1) {
            unsigned ov = __shfl_xor(kv, m, 64);
            kv = ov < kv ? ov : kv;
        }
        if (lm == 0)
            skey[wrow0 + (k >> 2) * 16 + lq4 * 4 + (k & 3)] = kv;
    }
    // no barrier: skey rows wave-private

    // ---- y·v_bsel via fragments + 4-shuffle reduce into sdot ----
    #pragma unroll
    for (int k = 0; k < 8; ++k) {
        const int row = wrow0 + (k >> 2) * 16 + lq4 * 4 + (k & 3);
        const unsigned bsel = skey[row] & 1023u;
        const float vlo = bits2f(((unsigned)(unsigned short)vbf[bsel * DZ + lm]) << 16);
        const float vhi = bits2f(((unsigned)(unsigned short)vbf[bsel * DZ + 16 + lm]) << 16);
        const float ylo = bits2f(ypkv[k] << 16);
        const float yhi = bits2f(ypkv[k] & 0xFFFF0000u);
        float p = fmaf(yhi, vhi, ylo * vlo);
        p += __shfl_xor(p, 1, 64);
        p += __shfl_xor(p, 2, 64);
        p += __shfl_xor(p, 4, 64);
        p += __shfl_xor(p, 8, 64);
        if (lm == 0) sdot[row] = p;
    }

    // ---- D: epilogue, lanes 0..31 handle the wave's 32 rows ----
    float rs = 0.0f, commit = 0.0f;
    if (l < 32) {
        const int rowb = wrow0 + l;
        const int rabs = blockIdx.x * ENC_ROWS + rowb;
        const unsigned kr = skey[rowb];
        const int bsel = (int)(kr & 1023u);
        const float score = bits2f(kr & 0xFFFFFC00u);
        bidx_out[rabs] = (unsigned short)bsel;

        float znorm = 0.0f;
        #pragma unroll
        for (int i = 0; i < 4; ++i) {
            uint4 q = *(const uint4*)&zbf[rowb * ZSTR + i * 8];
            zp[(size_t)(4 * i + 0) * N_ROWS + rabs] = q.x;
            zp[(size_t)(4 * i + 1) * N_ROWS + rabs] = q.y;
            zp[(size_t)(4 * i + 2) * N_ROWS + rabs] = q.z;
            zp[(size_t)(4 * i + 3) * N_ROWS + rabs] = q.w;
            float f0 = bits2f(q.x << 16), f1 = bits2f(q.x & 0xFFFF0000u);
            float f2 = bits2f(q.y << 16), f3 = bits2f(q.y & 0xFFFF0000u);
            float f4 = bits2f(q.z << 16), f5 = bits2f(q.z & 0xFFFF0000u);
            float f6 = bits2f(q.w << 16), f7 = bits2f(q.w & 0xFFFF0000u);
            znorm = fmaf(f0, f0, znorm); znorm = fmaf(f1, f1, znorm);
            znorm = fmaf(f2, f2, znorm); znorm = fmaf(f3, f3, znorm);
            znorm = fmaf(f4, f4, znorm); znorm = fmaf(f5, f5, znorm);
            znorm = fmaf(f6, f6, znorm); znorm = fmaf(f7, f7, znorm);
        }
        commit = znorm + (score - BIAS);
        rs = xnorm - 2.0f * (sdot[rowb] + xb) + munorm[bsel];
    }
    #pragma unroll
    for (int off = 32; off > 0; off >>= 1) {
        rs     += __shfl_down(rs, off, 64);
        commit += __shfl_down(commit, off, 64);
    }
    if (l == 0) {                       // plain stores, NO atomics
        rpart[blockIdx.x * 2 + w] = rs;
        cpart[blockIdx.x * 2 + w] = commit;
    }
}

// ---------- hist: r8-exact (17 roles x 64 chunks, NATIVE INT LDS atomics) ----
__global__ __launch_bounds__(256) void vq_hist(
    const unsigned* __restrict__ zp, const unsigned short* __restrict__ bidx,
    float* __restrict__ part)
{
    __shared__ int h[2 * NB];
    const int t = threadIdx.x;
    const int ci    = blockIdx.x % HROLES;
    const int chunk = blockIdx.x / HROLES;

    #pragma unroll
    for (int i = 0; i < 8; ++i) h[t + 256 * i] = 0;
    __syncthreads();

    const int base = chunk * HROWS;
    if (ci < 16) {
        const unsigned* zc = zp + (size_t)ci * N_ROWS;
        #pragma unroll 4
        for (int i = 0; i < HROWS / 256; ++i) {
            int r = base + t + 256 * i;
            unsigned w = zc[r];
            int b = bidx[r];
            atomicAdd(&h[b],      __float2int_rn(bits2f(w << 16) * HSCALE));
            atomicAdd(&h[b + NB], __float2int_rn(bits2f(w & 0xFFFF0000u) * HSCALE));
        }
        __syncthreads();
        float* pp = part + (size_t)chunk * PART_STRIDE + (size_t)(2 * ci) * NB;
        #pragma unroll
        for (int i = 0; i < 8; ++i)
            pp[t + 256 * i] = (float)h[t + 256 * i] * (1.0f / HSCALE);
    } else {
        #pragma unroll 4
        for (int i = 0; i < HROWS / 256; ++i) {
            int r = base + t + 256 * i;
            atomicAdd(&h[bidx[r]], 1);
        }
        __syncthreads();
        float* pp = part + (size_t)chunk * PART_STRIDE + (size_t)32 * NB;
        #pragma unroll
        for (int i = 0; i < 4; ++i) pp[t + 256 * i] = (float)h[t + 256 * i];
    }
}

// ---------- reduce + finalize-SCALAR only (132-block last-block-done) ----------
__global__ __launch_bounds__(256) void vq_redfin(
    const float* __restrict__ part, const float* __restrict__ assignments,
    float* __restrict__ ws, float* __restrict__ out)
{
    const int t = threadIdx.x;
    {
        const int o = blockIdx.x * 256 + t;          // 132 blocks -> 33792 outputs
        float s = 0.0f;
        #pragma unroll 8
        for (int c = 0; c < HCHUNKS; ++c)
            s += part[(size_t)c * PART_STRIDE + o];
        (ws + WS_SUMZC)[o] = s;                      // sumzc + counts contiguous
    }
    __shared__ int sdone;
    __threadfence();
    __syncthreads();
    if (t == 0) {
        unsigned old = atomicAdd((unsigned*)ws + WS_FINS + 2, 1u);
        sdone = ((old % (unsigned)RF_BLOCKS) == (unsigned)(RF_BLOCKS - 1)) ? 1 : 0;
    }
    __syncthreads();
    if (!sdone) return;
    __threadfence();

    __shared__ float h[2048];
    __shared__ float sred[4], cred[4];
    __shared__ int s_mx;
    const float* counts = ws + WS_COUNTS;

    {
        const float* rp = ws + WS_RPART;
        const float* cp = ws + WS_CPART;
        float rsum = 0.0f, csum = 0.0f;
        #pragma unroll
        for (int i = 0; i < 32; ++i) {               // 8192 / 256 = 32 each
            rsum += rp[t + 256 * i];
            csum += cp[t + 256 * i];
        }
        #pragma unroll
        for (int off = 32; off > 0; off >>= 1) {
            rsum += __shfl_down(rsum, off, 64);
            csum += __shfl_down(csum, off, 64);
        }
        if ((t & 63) == 0) { sred[t >> 6] = rsum; cred[t >> 6] = csum; }
    }

    float* af           = h;
    unsigned char* dd   = (unsigned char*)(h + 1024);
    int*   tsum         = (int*)(h + 1280);
    float* rv           = h + 1536;
    int*   ri           = (int*)(h + 1792);

    float cnt[4]; int dloc[4];
    float bestv = -1.0f; int besti = 0;
    #pragma unroll
    for (int u = 0; u < 4; ++u) {
        int b = 4 * t + u;
        float c = counts[b]; cnt[u] = c;
        float ba = c / NBF;
        float ae = 0.99f * assignments[b] + 0.01f * ba;
        af[b] = ae;
        int d = (ae * NBF < MIN_ASSIGN) ? 1 : 0;
        dd[b] = (unsigned char)d; dloc[u] = d;
        if (ba > bestv) { bestv = ba; besti = b; }
    }
    rv[t] = bestv; ri[t] = besti;
    __syncthreads();
    for (int s = 128; s > 0; s >>= 1) {
        if (t < s) {
            float ov = rv[t + s]; int oi = ri[t + s];
            if (ov > rv[t] || (ov == rv[t] && oi < ri[t])) { rv[t] = ov; ri[t] = oi; }
        }
        __syncthreads();
    }
    if (t == 0) s_mx = ri[0];
    __syncthreads();
    const int mx = s_mx;
    const float a0mx = af[mx];
    const int na_mx = dd[mx];

    tsum[t] = dloc[0] + dloc[1] + dloc[2] + dloc[3];
    __syncthreads();
    for (int off = 1; off < 256; off <<= 1) {
        int v2 = (t + off < 256) ? tsum[t + off] : 0;
        __syncthreads();
        tsum[t] += v2;
        __syncthreads();
    }
    const int K = tsum[0];
    const int Snext = (t < 255) ? tsum[t + 1] : 0;
    int suf[4];
    suf[3] = dloc[3]; suf[2] = dloc[2] + suf[3];
    suf[1] = dloc[1] + suf[2]; suf[0] = dloc[0] + suf[1];

    #pragma unroll
    for (int u = 0; u < 4; ++u) {
        int b = 4 * t + u;
        float av = af[b];
        int rank = suf[u] + Snext;
        int isd = dd[b];
        if (isd) av = ldexpf(a0mx, -rank);
        if (b == mx && K > 0) av = ldexpf(a0mx, -K);
        out[1 + NB * DZ + b] = av;
        ws[WS_FINS + 64 + b] = (float)isd;     // dead flag for vq_fin_vec
    }
    if (t == 0) {
        ((int*)ws)[WS_FINS] = mx;
        ws[WS_FINS + 1] = (float)na_mx;
        float rtot = sred[0] + sred[1] + sred[2] + sred[3];
        float ctot = cred[0] + cred[1] + cred[2] + cred[3];
        float recon = 0.5f * (rtot / NBF) + 32.0f * 1.8378770664093453f;
        float commit = ctot / (NBF * (float)DZ);
        out[0] = recon + 0.25f * commit;
    }
}

// ---------- finalize (vector part): 1024 bins x 32 comps, fully parallel ----------
__global__ __launch_bounds__(256) void vq_fin_vec(
    const float* __restrict__ vectors, const float* __restrict__ noise,
    const float* __restrict__ ws, float* __restrict__ out)
{
    const int idx = blockIdx.x * 256 + threadIdx.x;   // 128 blocks = 32768
    const int b = idx >> 5, c = idx & 31;
    const int mx = ((const int*)ws)[WS_FINS];
    const float na_mx = ws[WS_FINS + 1];
    const float isd = ws[WS_FINS + 64 + b];
    const float cnt = (ws + WS_COUNTS)[b];
    const float* sumzc = ws + WS_SUMZC;

    float v2 = vectors[b * DZ + c];
    if (isd != 0.0f) {
        const float mxn = (b < mx) ? na_mx : 0.0f;
        v2 = vectors[mx * DZ + c] + mxn * noise[mx * DZ + c] + noise[b * DZ + c];
    }
    float mean = (cnt == 0.0f) ? v2 : (sumzc[(size_t)c * NB + b] / cnt);
    out[1 + b * DZ + c] = 0.99f * v2 + 0.01f * mean;
}

// ---------- fallback (round-1) path, used only if ws is too small ----------
__global__ __launch_bounds__(64) void vq_prep_fb(
    const float* __restrict__ vectors, const float* __restrict__ W_dec,
    const float* __restrict__ b_dec, float* __restrict__ vnorm,
    float* __restrict__ mu_table)
{
    const int j = blockIdx.x;
    const int t = threadIdx.x;
    __shared__ float v[DZ];
    if (t < DZ) v[t] = vectors[j * DZ + t];
    __syncthreads();
    float m = b_dec[t];
    #pragma unroll
    for (int k = 0; k < DZ; ++k) m = fmaf(v[k], W_dec[k * DX + t], m);
    mu_table[(size_t)j * DX + t] = m;
    if (t == 0) {
        float s = 0.0f;
        #pragma unroll
        for (int k = 0; k < DZ; ++k) s = fmaf(v[k], v[k], s);
        vnorm[j] = s;
    }
}

__global__ __launch_bounds__(256) void vq_main_atomic(
    const float* __restrict__ x, const float* __restrict__ W_enc,
    const float* __restrict__ b_enc, const float* __restrict__ vectors,
    const float* __restrict__ vnorm, const float* __restrict__ mu_table,
    float* __restrict__ counts, float* __restrict__ sum_z,
    float* __restrict__ recon_acc, float* __restrict__ commit_acc)
{
    const int r = blockIdx.x * 256 + threadIdx.x;
    float xr[DX];
    const float4* xp = reinterpret_cast<const float4*>(x + (size_t)r * DX);
    #pragma unroll
    for (int i = 0; i < DX / 4; ++i) {
        float4 v = xp[i];
        xr[4 * i + 0] = v.x; xr[4 * i + 1] = v.y;
        xr[4 * i + 2] = v.z; xr[4 * i + 3] = v.w;
    }
    float z[DZ];
    #pragma unroll
    for (int c = 0; c < DZ; ++c) z[c] = b_enc[c];
    #pragma unroll
    for (int k = 0; k < DX; ++k) {
        float xk = xr[k];
        #pragma unroll
        for (int c = 0; c < DZ; ++c) z[c] = fmaf(xk, W_enc[k * DZ + c], z[c]);
    }
    float znorm = 0.0f;
    #pragma unroll
    for (int c = 0; c < DZ; ++c) znorm = fmaf(z[c], z[c], znorm);
    float zm2[DZ];
    #pragma unroll
    for (int c = 0; c < DZ; ++c) zm2[c] = -2.0f * z[c];

    float best = 3.4e38f;
    int bi = 0;
    for (int j = 0; j < NB; ++j) {
        const float* vj = vectors + j * DZ;
        float s0 = vnorm[j], s1 = 0.0f, s2 = 0.0f, s3 = 0.0f;
        #pragma unroll
        for (int c = 0; c < DZ; c += 4) {
            s0 = fmaf(zm2[c + 0], vj[c + 0], s0);
            s1 = fmaf(zm2[c + 1], vj[c + 1], s1);
            s2 = fmaf(zm2[c + 2], vj[c + 2], s2);
            s3 = fmaf(zm2[c + 3], vj[c + 3], s3);
        }
        float s = (s0 + s1) + (s2 + s3);
        if (s < best) { best = s; bi = j; }
    }
    float commit_row = znorm + best;

    float rs = 0.0f;
    const float4* mup = reinterpret_cast<const float4*>(mu_table + (size_t)bi * DX);
    #pragma unroll
    for (int i = 0; i < DX / 4; ++i) {
        float4 m = mup[i];
        float d0 = xr[4 * i + 0] - m.x; rs = fmaf(d0, d0, rs);
        float d1 = xr[4 * i + 1] - m.y; rs = fmaf(d1, d1, rs);
        float d2 = xr[4 * i + 2] - m.z; rs = fmaf(d2, d2, rs);
        float d3 = xr[4 * i + 3] - m.w; rs = fmaf(d3, d3, rs);
    }
    atomicAdd(&counts[bi], 1.0f);
    #pragma unroll
    for (int c = 0; c < DZ; ++c)
        atomicAdd(&sum_z[(size_t)bi * DZ + c], -0.5f * zm2[c]);
    #pragma unroll
    for (int off = 32; off > 0; off >>= 1) {
        rs += __shfl_down(rs, off, 64);
        commit_row += __shfl_down(commit_row, off, 64);
    }
    if ((threadIdx.x & 63) == 0) {
        atomicAdd(recon_acc, rs);
        atomicAdd(commit_acc, commit_row);
    }
}

__global__ __launch_bounds__(1024) void vq_finalize_fb(
    const float* __restrict__ vectors, const float* __restrict__ assignments,
    const float* __restrict__ noise, const float* __restrict__ counts,
    const float* __restrict__ sum_z, const float* __restrict__ recon_acc,
    const float* __restrict__ commit_acc, float* __restrict__ out)
{
    __shared__ float a[NB];
    __shared__ unsigned char na[NB];
    __shared__ float rv[NB];
    __shared__ int ri[NB];
    __shared__ int s_max_idx;
    const int t = threadIdx.x;

    const float cnt = counts[t];
    const float ba = cnt / NBF;
    const float ae = 0.99f * assignments[t] + 0.01f * ba;
    a[t] = ae;
    na[t] = (ae * NBF < MIN_ASSIGN) ? 1 : 0;
    rv[t] = ba; ri[t] = t;
    __syncthreads();
    for (int s = NB / 2; s > 0; s >>= 1) {
        if (t < s) {
            float ov = rv[t + s]; int oi = ri[t + s];
            if (ov > rv[t] || (ov == rv[t] && oi < ri[t])) { rv[t] = ov; ri[t] = oi; }
        }
        __syncthreads();
    }
    if (t == 0) s_max_idx = ri[0];
    __syncthreads();
    const int mx = s_max_idx;
    if (t == 0) {
        for (int i = NB - 1; i >= 0; --i) {
            if (na[i]) { float v = 0.5f * a[mx]; a[i] = v; a[mx] = v; }
        }
    }
    __syncthreads();
    out[1 + NB * DZ + t] = a[t];
    const bool dead = (na[t] != 0);
    #pragma unroll
    for (int c = 0; c < DZ; ++c) {
        float v2 = dead ? (vectors[mx * DZ + c] + noise[t * DZ + c])
                        : vectors[t * DZ + c];
        float mean = (cnt == 0.0f) ? v2 : (sum_z[(size_t)t * DZ + c] / cnt);
        out[1 + t * DZ + c] = 0.99f * v2 + 0.01f * mean;
    }
    if (t == 0) {
        float recon = 0.5f * (recon_acc[0] / NBF) + 32.0f * 1.8378770664093453f;
        float commit = commit_acc[0] / (NBF * (float)DZ);
        out[0] = recon + 0.25f * commit;
    }
}

extern "C" void kernel_launch(void* const* d_in, const int* in_sizes, int n_in,
                              void* d_out, int out_size, void* d_ws, size_t ws_size,
                              hipStream_t stream)
{
    const float* x           = (const float*)d_in[0];
    const float* W_enc       = (const float*)d_in[1];
    const float* b_enc       = (const float*)d_in[2];
    const float* vectors     = (const float*)d_in[3];
    const float* W_dec       = (const float*)d_in[4];
    const float* b_dec       = (const float*)d_in[5];
    const float* assignments = (const float*)d_in[6];
    const float* noise       = (const float*)d_in[7];
    float* out = (float*)d_out;
    float* ws  = (float*)d_ws;

    if (ws_size >= (size_t)WS_TOTAL * sizeof(float)) {
        vq_prep<<<NB, 64, 0, stream>>>(vectors, W_enc, W_dec, b_dec, ws);
        vq_encmin<<<ENC_BLOCKS, ENC_THREADS, 0, stream>>>(x,
            (const short*)(ws + WS_WENCT), b_enc,
            (const short*)(ws + WS_WDECB), b_dec,
            (const short*)(ws + WS_VBF), (const short*)(ws + WS_VBF2),
            ws + WS_VNORMB, ws + WS_MUNORM,
            (unsigned*)(ws + WS_ZP), (unsigned short*)(ws + WS_BIDX),
            ws + WS_RPART, ws + WS_CPART);
        vq_hist<<<HBLOCKS, 256, 0, stream>>>(
            (const unsigned*)(ws + WS_ZP),
            (const unsigned short*)(ws + WS_BIDX),
            ws + WS_PART);
        vq_redfin<<<RF_BLOCKS, 256, 0, stream>>>(
            ws + WS_PART, assignments, ws, out);
        vq_fin_vec<<<(NB * DZ) / 256, 256, 0, stream>>>(vectors, noise, ws, out);
    } else {
        zero_kernel<<<(FB_ZERO_N + 255) / 256, 256, 0, stream>>>(ws, FB_ZERO_N);
        vq_prep_fb<<<NB, 64, 0, stream>>>(vectors, W_dec, b_dec,
            ws + FB_VNORM, ws + FB_MUTAB);
        vq_main_atomic<<<N_ROWS / 256, 256, 0, stream>>>(x, W_enc, b_enc, vectors,
            ws + FB_VNORM, ws + FB_MUTAB, ws + FB_COUNTS, ws + FB_SUMZ,
            ws + FB_RECON, ws + FB_COMMIT);
        vq_finalize_fb<<<1, NB, 0, stream>>>(vectors, assignments, noise,
            ws + FB_COUNTS, ws + FB_SUMZ, ws + FB_RECON, ws + FB_COMMIT, out);
    }
}

// Round 12
// 197.962 us; speedup vs baseline: 1.0821x; 1.0821x over previous
//
#include <hip/hip_runtime.h>
#include <math.h>

// Problem constants (from reference setup_inputs)
#define N_ROWS 262144
#define DX 64
#define DZ 32
#define NB 1024
#define NBF 262144.0f
#define MIN_ASSIGN (0.1f / 1024.0f)
#define BIAS 512.0f

typedef short shortx8 __attribute__((ext_vector_type(8)));
typedef float floatx4 __attribute__((ext_vector_type(4)));

// ---------- fast-path workspace layout (float offsets) ----------
#define WS_VNORMB 64                       // + 1024  (‖v‖² + 512 bias)
#define WS_MUNORM 1088                     // + 1024
#define WS_WENCT  2112                     // + 1024  (32x64 bf16 W_enc^T)
#define WS_WDECB  3136                     // + 1024  (32x64 bf16 W_dec)
#define WS_VBF    4160                     // + 16384 (1024x32 bf16 v)
#define WS_VBF2   20544                    // + 16384 (1024x32 bf16 -2v)
#define WS_ZP     36928                    // + 4194304
#define WS_BIDX   4231232                  // + 131072
#define WS_SUMZC  4362304                  // + 32768
#define WS_COUNTS 4395072                  // + 1024
#define WS_PART   4396096                  // + 2162688
#define WS_FINS   6558784                  // [0]=mx,[1]=na_mx,[2]=done,[64..1088)=isd
#define WS_RPART  6559872                  // + 8192 (per-wave recon partials)
#define WS_CPART  6568064                  // + 8192
#define WS_TOTAL  6576256                  // floats (~26.3 MB)
#define PART_STRIDE 33792
#define HCHUNKS 64
#define HROWS  (N_ROWS / HCHUNKS)          // 4096
#define HROLES 17
#define HBLOCKS (HROLES * HCHUNKS)         // 1088
#define HSCALE 2048.0f
#define RF_BLOCKS 132
#define ENC_THREADS 128
#define ENC_ROWS 64                        // 64 rows/block = 32 rows/WAVE
#define ENC_BLOCKS (N_ROWS / ENC_ROWS)     // 4096
#define ZSTR 40                            // zbf row stride (shorts)

// ---------- fallback (round-1) workspace layout ----------
#define FB_RECON  0
#define FB_COMMIT 1
#define FB_COUNTS 64
#define FB_SUMZ   1088
#define FB_VNORM  33856
#define FB_MUTAB  34880
#define FB_ZERO_N 33856

static __device__ __forceinline__ short f2bf(float f) {
    union { float f; unsigned u; } v; v.f = f;
    unsigned r = v.u + 0x7FFFu + ((v.u >> 16) & 1u);   // RNE
    return (short)(r >> 16);
}
static __device__ __forceinline__ float bits2f(unsigned u) {
    union { unsigned u; float f; } v; v.u = u; return v.f;
}
static __device__ __forceinline__ unsigned pk2(float lo, float hi) {
    unsigned a = __builtin_bit_cast(unsigned, lo) + 0x8000u;
    unsigned b = __builtin_bit_cast(unsigned, hi) + 0x8000u;
    return __builtin_amdgcn_perm(b, a, 0x07060302u);
}

__global__ __launch_bounds__(256) void zero_kernel(float* __restrict__ p, int n) {
    int i = blockIdx.x * 256 + threadIdx.x;
    if (i < n) p[i] = 0.0f;
}

// Per-bin prep (unchanged): biased vnorm, munorm, bf16 codebooks, bf16 weights.
__global__ __launch_bounds__(64) void vq_prep(
    const float* __restrict__ vectors, const float* __restrict__ W_enc,
    const float* __restrict__ W_dec, const float* __restrict__ b_dec,
    float* __restrict__ ws)
{
    const int j = blockIdx.x;
    const int t = threadIdx.x;
    float* vnormb = ws + WS_VNORMB;
    float* munorm = ws + WS_MUNORM;
    short* vbf  = (short*)(ws + WS_VBF);
    short* vbf2 = (short*)(ws + WS_VBF2);
    short* wencT = (short*)(ws + WS_WENCT);
    short* wdecb = (short*)(ws + WS_WDECB);

    if (j == 0 && t == 2) ws[WS_FINS + 2] = 0.0f;      // redfin done counter
    if (j == 0) {
        #pragma unroll
        for (int c = 0; c < DZ; ++c)
            wencT[c * DX + t] = f2bf(W_enc[t * DZ + c]);
    }
    if (j == 1) {
        #pragma unroll
        for (int c = 0; c < DZ; ++c)
            wdecb[c * DX + t] = f2bf(W_dec[c * DX + t]);
    }

    __shared__ float v[DZ];
    if (t < DZ) {
        float vv = vectors[j * DZ + t];
        v[t] = vv;
        vbf[j * DZ + t]  = f2bf(vv);
        vbf2[j * DZ + t] = f2bf(-2.0f * vv);
    }
    __syncthreads();
    float m = b_dec[t];
    #pragma unroll
    for (int k = 0; k < DZ; ++k) m = fmaf(v[k], W_dec[k * DX + t], m);
    float ms = m * m;
    #pragma unroll
    for (int off = 32; off > 0; off >>= 1) ms += __shfl_down(ms, off, 64);
    if (t == 0) {
        munorm[j] = ms;
        float s = 0.0f;
        #pragma unroll
        for (int k = 0; k < DZ; ++k) s = fmaf(v[k], v[k], s);
        vnormb[j] = s + BIAS;
    }
}

// ---------- encmin v5: 32 rows/WAVE, barrier-free, SPILL-FREE ----------
// r11's v4 at __launch_bounds__(128,8) spilled (VGPR crushed to 32; WRITE_SIZE
// 17->101MB of scratch traffic; encmin 44->92us). v5: (128,6) -> VGPR cap ~84,
// 24 waves/CU; phase-B weight fragments loaded in TWO waves (z-weights, then
// y-weights) so the register peak stays ~60 < 84. Still zero barriers.
__global__ __launch_bounds__(ENC_THREADS, 6) void vq_encmin(
    const float* __restrict__ x, const short* __restrict__ wencT,
    const float* __restrict__ b_enc, const short* __restrict__ wdecb,
    const float* __restrict__ b_dec, const short* __restrict__ vbf,
    const short* __restrict__ vbf2, const float* __restrict__ vnormb,
    const float* __restrict__ munorm,
    unsigned* __restrict__ zp, unsigned short* __restrict__ bidx_out,
    float* __restrict__ rpart, float* __restrict__ cpart)
{
    __shared__ __attribute__((aligned(16))) short zbf[ENC_ROWS * ZSTR]; // 5120 B
    __shared__ unsigned skey[ENC_ROWS];                                 // 256 B
    __shared__ float sdot[ENC_ROWS];                                    // 256 B

    const int t = threadIdx.x;
    const int w = t >> 6, l = t & 63, lm = l & 15, lq4 = l >> 4;
    const int wrow0 = w * 32;                        // wave's first block-local row
    const int rowbase = blockIdx.x * ENC_ROWS + wrow0;  // absolute

    const float be0 = b_enc[lm], be1 = b_enc[16 + lm];
    const float4 bd0 = *(const float4*)(b_dec + lq4 * 8);
    const float4 bd1 = *(const float4*)(b_dec + lq4 * 8 + 4);
    const float4 bd2 = *(const float4*)(b_dec + 32 + lq4 * 8);
    const float4 bd3 = *(const float4*)(b_dec + 32 + lq4 * 8 + 4);

    float xnorm = 0.0f, xb = 0.0f;
    unsigned ypkv[8];

    // ---- B: per row-tile, stage x->frags; z MFMAs (we only), then y (wd only) ----
    #pragma unroll
    for (int rt = 0; rt < 2; ++rt) {
        const float* xr = x + (size_t)(rowbase + rt * 16 + lm) * DX + lq4 * 8;
        const float4 v0 = *(const float4*)(xr);
        const float4 v1 = *(const float4*)(xr + 4);
        const float4 v2 = *(const float4*)(xr + 32);
        const float4 v3 = *(const float4*)(xr + 36);

        // partial xnorm / x·b_dec over this lane's 16 cols (fp32)
        float pn = v0.x*v0.x + v0.y*v0.y + v0.z*v0.z + v0.w*v0.w
                 + v1.x*v1.x + v1.y*v1.y + v1.z*v1.z + v1.w*v1.w
                 + v2.x*v2.x + v2.y*v2.y + v2.z*v2.z + v2.w*v2.w
                 + v3.x*v3.x + v3.y*v3.y + v3.z*v3.z + v3.w*v3.w;
        float pb = v0.x*bd0.x + v0.y*bd0.y + v0.z*bd0.z + v0.w*bd0.w
                 + v1.x*bd1.x + v1.y*bd1.y + v1.z*bd1.z + v1.w*bd1.w
                 + v2.x*bd2.x + v2.y*bd2.y + v2.z*bd2.z + v2.w*bd2.w
                 + v3.x*bd3.x + v3.y*bd3.y + v3.z*bd3.z + v3.w*bd3.w;
        pn += __shfl_xor(pn, 16, 64); pn += __shfl_xor(pn, 32, 64);
        pb += __shfl_xor(pb, 16, 64); pb += __shfl_xor(pb, 32, 64);
        if (rt == lq4) { xnorm = pn; xb = pb; }      // lane's own row (l<32 valid)

        // pack to bf16 A-fragments (cols 0-31 | 32-63, this lane's lq4 slice)
        union { uint2 q[2]; shortx8 s; } ax0, ax1;
        ax0.q[0] = (uint2){pk2(v0.x, v0.y), pk2(v0.z, v0.w)};
        ax0.q[1] = (uint2){pk2(v1.x, v1.y), pk2(v1.z, v1.w)};
        ax1.q[0] = (uint2){pk2(v2.x, v2.y), pk2(v2.z, v2.w)};
        ax1.q[1] = (uint2){pk2(v3.x, v3.y), pk2(v3.z, v3.w)};

        // -- z pass (we fragments only; L1-hot 4KB table) --
        {
            const shortx8 we00 = *(const shortx8*)&wencT[(0 * 16 + lm) * DX + 0 * 32 + lq4 * 8];
            const shortx8 we01 = *(const shortx8*)&wencT[(0 * 16 + lm) * DX + 1 * 32 + lq4 * 8];
            const shortx8 we10 = *(const shortx8*)&wencT[(1 * 16 + lm) * DX + 0 * 32 + lq4 * 8];
            const shortx8 we11 = *(const shortx8*)&wencT[(1 * 16 + lm) * DX + 1 * 32 + lq4 * 8];
            floatx4 z0 = {be0, be0, be0, be0}, z1 = {be1, be1, be1, be1};
            z0 = __builtin_amdgcn_mfma_f32_16x16x32_bf16(ax0.s, we00, z0, 0, 0, 0);
            z0 = __builtin_amdgcn_mfma_f32_16x16x32_bf16(ax1.s, we01, z0, 0, 0, 0);
            z1 = __builtin_amdgcn_mfma_f32_16x16x32_bf16(ax0.s, we10, z1, 0, 0, 0);
            z1 = __builtin_amdgcn_mfma_f32_16x16x32_bf16(ax1.s, we11, z1, 0, 0, 0);
            #pragma unroll
            for (int reg = 0; reg < 4; ++reg) {
                const int row = wrow0 + rt * 16 + lq4 * 4 + reg;   // wave-private
                const unsigned zpk = pk2(z0[reg], z1[reg]);
                zbf[row * ZSTR + lm]      = (short)(zpk & 0xFFFFu);
                zbf[row * ZSTR + 16 + lm] = (short)(zpk >> 16);
            }
        }
        // -- y pass (wd fragments only) --
        {
            const shortx8 wd00 = *(const shortx8*)&wdecb[(0 * 16 + lm) * DX + 0 * 32 + lq4 * 8];
            const shortx8 wd01 = *(const shortx8*)&wdecb[(0 * 16 + lm) * DX + 1 * 32 + lq4 * 8];
            const shortx8 wd10 = *(const shortx8*)&wdecb[(1 * 16 + lm) * DX + 0 * 32 + lq4 * 8];
            const shortx8 wd11 = *(const shortx8*)&wdecb[(1 * 16 + lm) * DX + 1 * 32 + lq4 * 8];
            floatx4 y0 = {0.f, 0.f, 0.f, 0.f}, y1 = {0.f, 0.f, 0.f, 0.f};
            y0 = __builtin_amdgcn_mfma_f32_16x16x32_bf16(ax0.s, wd00, y0, 0, 0, 0);
            y0 = __builtin_amdgcn_mfma_f32_16x16x32_bf16(ax1.s, wd01, y0, 0, 0, 0);
            y1 = __builtin_amdgcn_mfma_f32_16x16x32_bf16(ax0.s, wd10, y1, 0, 0, 0);
            y1 = __builtin_amdgcn_mfma_f32_16x16x32_bf16(ax1.s, wd11, y1, 0, 0, 0);
            #pragma unroll
            for (int reg = 0; reg < 4; ++reg)
                ypkv[rt * 4 + reg] = pk2(y0[reg], y1[reg]);
        }
    }
    // no barrier: zbf rows written/read by the SAME wave only

    // ---- C: MFMA argmin over 1024 codes ----
    shortx8 afrag[2];
    #pragma unroll
    for (int rt = 0; rt < 2; ++rt)
        afrag[rt] = *(const shortx8*)&zbf[(wrow0 + rt * 16 + lm) * ZSTR + lq4 * 8];

    unsigned key[8];
    #pragma unroll
    for (int k = 0; k < 8; ++k) key[k] = 0xFFFFFFFFu;

    #pragma unroll 4
    for (int jt = 0; jt < 64; ++jt) {
        const int jbase = jt * 16 + lm;
        const shortx8 bfrag = *(const shortx8*)&vbf2[(size_t)jbase * DZ + lq4 * 8];
        const float vn = vnormb[jbase];
        floatx4 cin = {vn, vn, vn, vn};
        #pragma unroll
        for (int rt = 0; rt < 2; ++rt) {
            floatx4 acc = __builtin_amdgcn_mfma_f32_16x16x32_bf16(
                afrag[rt], bfrag, cin, 0, 0, 0);
            #pragma unroll
            for (int reg = 0; reg < 4; ++reg) {
                unsigned u = __builtin_bit_cast(unsigned, acc[reg]);
                unsigned pk = (u & 0xFFFFFC00u) | (unsigned)jbase;
                int k = rt * 4 + reg;
                key[k] = key[k] < pk ? key[k] : pk;
            }
        }
    }

    // cross-lane min over the 16 columns (lm bits); ties -> smaller j
    #pragma unroll
    for (int k = 0; k < 8; ++k) {
        unsigned kv = key[k];
        #pragma unroll
        for (int m = 1; m <= 8; m <<= 1) {
            unsigned ov = __shfl_xor(kv, m, 64);
            kv = ov < kv ? ov : kv;
        }
        if (lm == 0)
            skey[wrow0 + (k >> 2) * 16 + lq4 * 4 + (k & 3)] = kv;
    }
    // no barrier: skey rows wave-private

    // ---- y·v_bsel via fragments + 4-shuffle reduce into sdot ----
    #pragma unroll
    for (int k = 0; k < 8; ++k) {
        const int row = wrow0 + (k >> 2) * 16 + lq4 * 4 + (k & 3);
        const unsigned bsel = skey[row] & 1023u;
        const float vlo = bits2f(((unsigned)(unsigned short)vbf[bsel * DZ + lm]) << 16);
        const float vhi = bits2f(((unsigned)(unsigned short)vbf[bsel * DZ + 16 + lm]) << 16);
        const float ylo = bits2f(ypkv[k] << 16);
        const float yhi = bits2f(ypkv[k] & 0xFFFF0000u);
        float p = fmaf(yhi, vhi, ylo * vlo);
        p += __shfl_xor(p, 1, 64);
        p += __shfl_xor(p, 2, 64);
        p += __shfl_xor(p, 4, 64);
        p += __shfl_xor(p, 8, 64);
        if (lm == 0) sdot[row] = p;
    }

    // ---- D: epilogue, lanes 0..31 handle the wave's 32 rows ----
    float rs = 0.0f, commit = 0.0f;
    if (l < 32) {
        const int rowb = wrow0 + l;
        const int rabs = blockIdx.x * ENC_ROWS + rowb;
        const unsigned kr = skey[rowb];
        const int bsel = (int)(kr & 1023u);
        const float score = bits2f(kr & 0xFFFFFC00u);
        bidx_out[rabs] = (unsigned short)bsel;

        float znorm = 0.0f;
        #pragma unroll
        for (int i = 0; i < 4; ++i) {
            uint4 q = *(const uint4*)&zbf[rowb * ZSTR + i * 8];
            zp[(size_t)(4 * i + 0) * N_ROWS + rabs] = q.x;
            zp[(size_t)(4 * i + 1) * N_ROWS + rabs] = q.y;
            zp[(size_t)(4 * i + 2) * N_ROWS + rabs] = q.z;
            zp[(size_t)(4 * i + 3) * N_ROWS + rabs] = q.w;
            float f0 = bits2f(q.x << 16), f1 = bits2f(q.x & 0xFFFF0000u);
            float f2 = bits2f(q.y << 16), f3 = bits2f(q.y & 0xFFFF0000u);
            float f4 = bits2f(q.z << 16), f5 = bits2f(q.z & 0xFFFF0000u);
            float f6 = bits2f(q.w << 16), f7 = bits2f(q.w & 0xFFFF0000u);
            znorm = fmaf(f0, f0, znorm); znorm = fmaf(f1, f1, znorm);
            znorm = fmaf(f2, f2, znorm); znorm = fmaf(f3, f3, znorm);
            znorm = fmaf(f4, f4, znorm); znorm = fmaf(f5, f5, znorm);
            znorm = fmaf(f6, f6, znorm); znorm = fmaf(f7, f7, znorm);
        }
        commit = znorm + (score - BIAS);
        rs = xnorm - 2.0f * (sdot[rowb] + xb) + munorm[bsel];
    }
    #pragma unroll
    for (int off = 32; off > 0; off >>= 1) {
        rs     += __shfl_down(rs, off, 64);
        commit += __shfl_down(commit, off, 64);
    }
    if (l == 0) {                       // plain stores, NO atomics
        rpart[blockIdx.x * 2 + w] = rs;
        cpart[blockIdx.x * 2 + w] = commit;
    }
}

// ---------- hist: r8-exact (17 roles x 64 chunks, NATIVE INT LDS atomics) ----
__global__ __launch_bounds__(256) void vq_hist(
    const unsigned* __restrict__ zp, const unsigned short* __restrict__ bidx,
    float* __restrict__ part)
{
    __shared__ int h[2 * NB];
    const int t = threadIdx.x;
    const int ci    = blockIdx.x % HROLES;
    const int chunk = blockIdx.x / HROLES;

    #pragma unroll
    for (int i = 0; i < 8; ++i) h[t + 256 * i] = 0;
    __syncthreads();

    const int base = chunk * HROWS;
    if (ci < 16) {
        const unsigned* zc = zp + (size_t)ci * N_ROWS;
        #pragma unroll 4
        for (int i = 0; i < HROWS / 256; ++i) {
            int r = base + t + 256 * i;
            unsigned w = zc[r];
            int b = bidx[r];
            atomicAdd(&h[b],      __float2int_rn(bits2f(w << 16) * HSCALE));
            atomicAdd(&h[b + NB], __float2int_rn(bits2f(w & 0xFFFF0000u) * HSCALE));
        }
        __syncthreads();
        float* pp = part + (size_t)chunk * PART_STRIDE + (size_t)(2 * ci) * NB;
        #pragma unroll
        for (int i = 0; i < 8; ++i)
            pp[t + 256 * i] = (float)h[t + 256 * i] * (1.0f / HSCALE);
    } else {
        #pragma unroll 4
        for (int i = 0; i < HROWS / 256; ++i) {
            int r = base + t + 256 * i;
            atomicAdd(&h[bidx[r]], 1);
        }
        __syncthreads();
        float* pp = part + (size_t)chunk * PART_STRIDE + (size_t)32 * NB;
        #pragma unroll
        for (int i = 0; i < 4; ++i) pp[t + 256 * i] = (float)h[t + 256 * i];
    }
}

// ---------- reduce + finalize-SCALAR only (132-block last-block-done) ----------
__global__ __launch_bounds__(256) void vq_redfin(
    const float* __restrict__ part, const float* __restrict__ assignments,
    float* __restrict__ ws, float* __restrict__ out)
{
    const int t = threadIdx.x;
    {
        const int o = blockIdx.x * 256 + t;          // 132 blocks -> 33792 outputs
        float s = 0.0f;
        #pragma unroll 8
        for (int c = 0; c < HCHUNKS; ++c)
            s += part[(size_t)c * PART_STRIDE + o];
        (ws + WS_SUMZC)[o] = s;                      // sumzc + counts contiguous
    }
    __shared__ int sdone;
    __threadfence();
    __syncthreads();
    if (t == 0) {
        unsigned old = atomicAdd((unsigned*)ws + WS_FINS + 2, 1u);
        sdone = ((old % (unsigned)RF_BLOCKS) == (unsigned)(RF_BLOCKS - 1)) ? 1 : 0;
    }
    __syncthreads();
    if (!sdone) return;
    __threadfence();

    __shared__ float h[2048];
    __shared__ float sred[4], cred[4];
    __shared__ int s_mx;
    const float* counts = ws + WS_COUNTS;

    {
        const float* rp = ws + WS_RPART;
        const float* cp = ws + WS_CPART;
        float rsum = 0.0f, csum = 0.0f;
        #pragma unroll
        for (int i = 0; i < 32; ++i) {               // 8192 / 256 = 32 each
            rsum += rp[t + 256 * i];
            csum += cp[t + 256 * i];
        }
        #pragma unroll
        for (int off = 32; off > 0; off >>= 1) {
            rsum += __shfl_down(rsum, off, 64);
            csum += __shfl_down(csum, off, 64);
        }
        if ((t & 63) == 0) { sred[t >> 6] = rsum; cred[t >> 6] = csum; }
    }

    float* af           = h;
    unsigned char* dd   = (unsigned char*)(h + 1024);
    int*   tsum         = (int*)(h + 1280);
    float* rv           = h + 1536;
    int*   ri           = (int*)(h + 1792);

    float cnt[4]; int dloc[4];
    float bestv = -1.0f; int besti = 0;
    #pragma unroll
    for (int u = 0; u < 4; ++u) {
        int b = 4 * t + u;
        float c = counts[b]; cnt[u] = c;
        float ba = c / NBF;
        float ae = 0.99f * assignments[b] + 0.01f * ba;
        af[b] = ae;
        int d = (ae * NBF < MIN_ASSIGN) ? 1 : 0;
        dd[b] = (unsigned char)d; dloc[u] = d;
        if (ba > bestv) { bestv = ba; besti = b; }
    }
    rv[t] = bestv; ri[t] = besti;
    __syncthreads();
    for (int s = 128; s > 0; s >>= 1) {
        if (t < s) {
            float ov = rv[t + s]; int oi = ri[t + s];
            if (ov > rv[t] || (ov == rv[t] && oi < ri[t])) { rv[t] = ov; ri[t] = oi; }
        }
        __syncthreads();
    }
    if (t == 0) s_mx = ri[0];
    __syncthreads();
    const int mx = s_mx;
    const float a0mx = af[mx];
    const int na_mx = dd[mx];

    tsum[t] = dloc[0] + dloc[1] + dloc[2] + dloc[3];
    __syncthreads();
    for (int off = 1; off < 256; off <<= 1) {
        int v2 = (t + off < 256) ? tsum[t + off] : 0;
        __syncthreads();
        tsum[t] += v2;
        __syncthreads();
    }
    const int K = tsum[0];
    const int Snext = (t < 255) ? tsum[t + 1] : 0;
    int suf[4];
    suf[3] = dloc[3]; suf[2] = dloc[2] + suf[3];
    suf[1] = dloc[1] + suf[2]; suf[0] = dloc[0] + suf[1];

    #pragma unroll
    for (int u = 0; u < 4; ++u) {
        int b = 4 * t + u;
        float av = af[b];
        int rank = suf[u] + Snext;
        int isd = dd[b];
        if (isd) av = ldexpf(a0mx, -rank);
        if (b == mx && K > 0) av = ldexpf(a0mx, -K);
        out[1 + NB * DZ + b] = av;
        ws[WS_FINS + 64 + b] = (float)isd;     // dead flag for vq_fin_vec
    }
    if (t == 0) {
        ((int*)ws)[WS_FINS] = mx;
        ws[WS_FINS + 1] = (float)na_mx;
        float rtot = sred[0] + sred[1] + sred[2] + sred[3];
        float ctot = cred[0] + cred[1] + cred[2] + cred[3];
        float recon = 0.5f * (rtot / NBF) + 32.0f * 1.8378770664093453f;
        float commit = ctot / (NBF * (float)DZ);
        out[0] = recon + 0.25f * commit;
    }
}

// ---------- finalize (vector part): 1024 bins x 32 comps, fully parallel ----------
__global__ __launch_bounds__(256) void vq_fin_vec(
    const float* __restrict__ vectors, const float* __restrict__ noise,
    const float* __restrict__ ws, float* __restrict__ out)
{
    const int idx = blockIdx.x * 256 + threadIdx.x;   // 128 blocks = 32768
    const int b = idx >> 5, c = idx & 31;
    const int mx = ((const int*)ws)[WS_FINS];
    const float na_mx = ws[WS_FINS + 1];
    const float isd = ws[WS_FINS + 64 + b];
    const float cnt = (ws + WS_COUNTS)[b];
    const float* sumzc = ws + WS_SUMZC;

    float v2 = vectors[b * DZ + c];
    if (isd != 0.0f) {
        const float mxn = (b < mx) ? na_mx : 0.0f;
        v2 = vectors[mx * DZ + c] + mxn * noise[mx * DZ + c] + noise[b * DZ + c];
    }
    float mean = (cnt == 0.0f) ? v2 : (sumzc[(size_t)c * NB + b] / cnt);
    out[1 + b * DZ + c] = 0.99f * v2 + 0.01f * mean;
}

// ---------- fallback (round-1) path, used only if ws is too small ----------
__global__ __launch_bounds__(64) void vq_prep_fb(
    const float* __restrict__ vectors, const float* __restrict__ W_dec,
    const float* __restrict__ b_dec, float* __restrict__ vnorm,
    float* __restrict__ mu_table)
{
    const int j = blockIdx.x;
    const int t = threadIdx.x;
    __shared__ float v[DZ];
    if (t < DZ) v[t] = vectors[j * DZ + t];
    __syncthreads();
    float m = b_dec[t];
    #pragma unroll
    for (int k = 0; k < DZ; ++k) m = fmaf(v[k], W_dec[k * DX + t], m);
    mu_table[(size_t)j * DX + t] = m;
    if (t == 0) {
        float s = 0.0f;
        #pragma unroll
        for (int k = 0; k < DZ; ++k) s = fmaf(v[k], v[k], s);
        vnorm[j] = s;
    }
}

__global__ __launch_bounds__(256) void vq_main_atomic(
    const float* __restrict__ x, const float* __restrict__ W_enc,
    const float* __restrict__ b_enc, const float* __restrict__ vectors,
    const float* __restrict__ vnorm, const float* __restrict__ mu_table,
    float* __restrict__ counts, float* __restrict__ sum_z,
    float* __restrict__ recon_acc, float* __restrict__ commit_acc)
{
    const int r = blockIdx.x * 256 + threadIdx.x;
    float xr[DX];
    const float4* xp = reinterpret_cast<const float4*>(x + (size_t)r * DX);
    #pragma unroll
    for (int i = 0; i < DX / 4; ++i) {
        float4 v = xp[i];
        xr[4 * i + 0] = v.x; xr[4 * i + 1] = v.y;
        xr[4 * i + 2] = v.z; xr[4 * i + 3] = v.w;
    }
    float z[DZ];
    #pragma unroll
    for (int c = 0; c < DZ; ++c) z[c] = b_enc[c];
    #pragma unroll
    for (int k = 0; k < DX; ++k) {
        float xk = xr[k];
        #pragma unroll
        for (int c = 0; c < DZ; ++c) z[c] = fmaf(xk, W_enc[k * DZ + c], z[c]);
    }
    float znorm = 0.0f;
    #pragma unroll
    for (int c = 0; c < DZ; ++c) znorm = fmaf(z[c], z[c], znorm);
    float zm2[DZ];
    #pragma unroll
    for (int c = 0; c < DZ; ++c) zm2[c] = -2.0f * z[c];

    float best = 3.4e38f;
    int bi = 0;
    for (int j = 0; j < NB; ++j) {
        const float* vj = vectors + j * DZ;
        float s0 = vnorm[j], s1 = 0.0f, s2 = 0.0f, s3 = 0.0f;
        #pragma unroll
        for (int c = 0; c < DZ; c += 4) {
            s0 = fmaf(zm2[c + 0], vj[c + 0], s0);
            s1 = fmaf(zm2[c + 1], vj[c + 1], s1);
            s2 = fmaf(zm2[c + 2], vj[c + 2], s2);
            s3 = fmaf(zm2[c + 3], vj[c + 3], s3);
        }
        float s = (s0 + s1) + (s2 + s3);
        if (s < best) { best = s; bi = j; }
    }
    float commit_row = znorm + best;

    float rs = 0.0f;
    const float4* mup = reinterpret_cast<const float4*>(mu_table + (size_t)bi * DX);
    #pragma unroll
    for (int i = 0; i < DX / 4; ++i) {
        float4 m = mup[i];
        float d0 = xr[4 * i + 0] - m.x; rs = fmaf(d0, d0, rs);
        float d1 = xr[4 * i + 1] - m.y; rs = fmaf(d1, d1, rs);
        float d2 = xr[4 * i + 2] - m.z; rs = fmaf(d2, d2, rs);
        float d3 = xr[4 * i + 3] - m.w; rs = fmaf(d3, d3, rs);
    }
    atomicAdd(&counts[bi], 1.0f);
    #pragma unroll
    for (int c = 0; c < DZ; ++c)
        atomicAdd(&sum_z[(size_t)bi * DZ + c], -0.5f * zm2[c]);
    #pragma unroll
    for (int off = 32; off > 0; off >>= 1) {
        rs += __shfl_down(rs, off, 64);
        commit_row += __shfl_down(commit_row, off, 64);
    }
    if ((threadIdx.x & 63) == 0) {
        atomicAdd(recon_acc, rs);
        atomicAdd(commit_acc, commit_row);
    }
}

__global__ __launch_bounds__(1024) void vq_finalize_fb(
    const float* __restrict__ vectors, const float* __restrict__ assignments,
    const float* __restrict__ noise, const float* __restrict__ counts,
    const float* __restrict__ sum_z, const float* __restrict__ recon_acc,
    const float* __restrict__ commit_acc, float* __restrict__ out)
{
    __shared__ float a[NB];
    __shared__ unsigned char na[NB];
    __shared__ float rv[NB];
    __shared__ int ri[NB];
    __shared__ int s_max_idx;
    const int t = threadIdx.x;

    const float cnt = counts[t];
    const float ba = cnt / NBF;
    const float ae = 0.99f * assignments[t] + 0.01f * ba;
    a[t] = ae;
    na[t] = (ae * NBF < MIN_ASSIGN) ? 1 : 0;
    rv[t] = ba; ri[t] = t;
    __syncthreads();
    for (int s = NB / 2; s > 0; s >>= 1) {
        if (t < s) {
            float ov = rv[t + s]; int oi = ri[t + s];
            if (ov > rv[t] || (ov == rv[t] && oi < ri[t])) { rv[t] = ov; ri[t] = oi; }
        }
        __syncthreads();
    }
    if (t == 0) s_max_idx = ri[0];
    __syncthreads();
    const int mx = s_max_idx;
    if (t == 0) {
        for (int i = NB - 1; i >= 0; --i) {
            if (na[i]) { float v = 0.5f * a[mx]; a[i] = v; a[mx] = v; }
        }
    }
    __syncthreads();
    out[1 + NB * DZ + t] = a[t];
    const bool dead = (na[t] != 0);
    #pragma unroll
    for (int c = 0; c < DZ; ++c) {
        float v2 = dead ? (vectors[mx * DZ + c] + noise[t * DZ + c])
                        : vectors[t * DZ + c];
        float mean = (cnt == 0.0f) ? v2 : (sum_z[(size_t)t * DZ + c] / cnt);
        out[1 + t * DZ + c] = 0.99f * v2 + 0.01f * mean;
    }
    if (t == 0) {
        float recon = 0.5f * (recon_acc[0] / NBF) + 32.0f * 1.8378770664093453f;
        float commit = commit_acc[0] / (NBF * (float)DZ);
        out[0] = recon + 0.25f * commit;
    }
}

extern "C" void kernel_launch(void* const* d_in, const int* in_sizes, int n_in,
                              void* d_out, int out_size, void* d_ws, size_t ws_size,
                              hipStream_t stream)
{
    const float* x           = (const float*)d_in[0];
    const float* W_enc       = (const float*)d_in[1];
    const float* b_enc       = (const float*)d_in[2];
    const float* vectors     = (const float*)d_in[3];
    const float* W_dec       = (const float*)d_in[4];
    const float* b_dec       = (const float*)d_in[5];
    const float* assignments = (const float*)d_in[6];
    const float* noise       = (const float*)d_in[7];
    float* out = (float*)d_out;
    float* ws  = (float*)d_ws;

    if (ws_size >= (size_t)WS_TOTAL * sizeof(float)) {
        vq_prep<<<NB, 64, 0, stream>>>(vectors, W_enc, W_dec, b_dec, ws);
        vq_encmin<<<ENC_BLOCKS, ENC_THREADS, 0, stream>>>(x,
            (const short*)(ws + WS_WENCT), b_enc,
            (const short*)(ws + WS_WDECB), b_dec,
            (const short*)(ws + WS_VBF), (const short*)(ws + WS_VBF2),
            ws + WS_VNORMB, ws + WS_MUNORM,
            (unsigned*)(ws + WS_ZP), (unsigned short*)(ws + WS_BIDX),
            ws + WS_RPART, ws + WS_CPART);
        vq_hist<<<HBLOCKS, 256, 0, stream>>>(
            (const unsigned*)(ws + WS_ZP),
            (const unsigned short*)(ws + WS_BIDX),
            ws + WS_PART);
        vq_redfin<<<RF_BLOCKS, 256, 0, stream>>>(
            ws + WS_PART, assignments, ws, out);
        vq_fin_vec<<<(NB * DZ) / 256, 256, 0, stream>>>(vectors, noise, ws, out);
    } else {
        zero_kernel<<<(FB_ZERO_N + 255) / 256, 256, 0, stream>>>(ws, FB_ZERO_N);
        vq_prep_fb<<<NB, 64, 0, stream>>>(vectors, W_dec, b_dec,
            ws + FB_VNORM, ws + FB_MUTAB);
        vq_main_atomic<<<N_ROWS / 256, 256, 0, stream>>>(x, W_enc, b_enc, vectors,
            ws + FB_VNORM, ws + FB_MUTAB, ws + FB_COUNTS, ws + FB_SUMZ,
            ws + FB_RECON, ws + FB_COMMIT);
        vq_finalize_fb<<<1, NB, 0, stream>>>(vectors, assignments, noise,
            ws + FB_COUNTS, ws + FB_SUMZ, ws + FB_RECON, ws + FB_COMMIT, out);
    }
}

// Round 13
// 161.390 us; speedup vs baseline: 1.3273x; 1.2266x over previous
//
#include <hip/hip_runtime.h>
#include <math.h>

// Problem constants (from reference setup_inputs)
#define N_ROWS 262144
#define DX 64
#define DZ 32
#define NB 1024
#define NBF 262144.0f
#define MIN_ASSIGN (0.1f / 1024.0f)
#define BIAS 512.0f

typedef short shortx8 __attribute__((ext_vector_type(8)));
typedef float floatx4 __attribute__((ext_vector_type(4)));
typedef float floatx2 __attribute__((ext_vector_type(2)));

// ---------- fast-path workspace layout (float offsets) ----------
#define WS_VNORMB 64                       // + 1024  (‖v‖² + 512 bias, f32 v)
#define WS_MUNORM 1088                     // + 1024  (‖mu_j‖², includes b_dec)
#define WS_WENCT  2112                     // + 1024  (32x64 bf16 = W_enc^T)
#define WS_WDECB  3136                     // + 1024  (32x64 bf16 = W_dec)
#define WS_VBF    4160                     // + 16384 (1024x32 bf16 v)
#define WS_VBF2   20544                    // + 16384 (1024x32 bf16 -2v)
#define WS_ZP     36928                    // + 4194304 (16 planes of bf16-pair z)
#define WS_BIDX   4231232                  // + 131072 (262144 u16)
#define WS_SUMZC  4362304                  // + 32768 (comp-major z sums)
#define WS_COUNTS 4395072                  // + 1024 (contiguous after SUMZC)
#define WS_PART   4396096                  // + 64*33792 = 2162688
#define WS_FINS   6558784                  // [0]=mx, [1]=na_mx, [2]=done ctr, [64..64+1024)=isd
#define WS_RPART  6559872                  // + 4096 (per-wave recon partials)
#define WS_CPART  6563968                  // + 4096 (per-wave commit partials)
#define WS_TOTAL  6568064                  // floats (~26.3 MB)
#define PART_STRIDE 33792
#define HCHUNKS 64
#define HROWS  (N_ROWS / HCHUNKS)          // 4096 rows per chunk
#define HROLES 17                          // 16 dual-comp roles + counts
#define HBLOCKS (HROLES * HCHUNKS)         // 1088
#define HSCALE 2048.0f                     // fixed-point scale for int LDS atomics
#define RF_BLOCKS 132                      // 132 * 256 = 33792 outputs
#define ENC_THREADS 128
#define ENC_BLOCKS (N_ROWS / ENC_THREADS)  // 2048

// ---------- encmin LDS layout (bytes), 128 rows/block (r8/r10-proven) ----------
#define XSTR 68                            // xbf row stride (shorts), 136 B
#define ZSTR 40                            // zbf row stride (shorts), 80 B
#define YSTR 36                            // ybf row stride (shorts), 72 B
#define SMEM_ZBF  0                        // 128*80  = 10240
#define SMEM_YBF  10240                    // 128*72  = 9216 (ends 19456)
#define SMEM_XBF  0                        // 128*136 = 17408 (aliases zbf+ybf)
#define SMEM_SKEY 19456                    // 512
#define SMEM_SZ   19968                    // 8 blocks/CU by LDS

// ---------- fallback (round-1) workspace layout ----------
#define FB_RECON  0
#define FB_COMMIT 1
#define FB_COUNTS 64
#define FB_SUMZ   1088
#define FB_VNORM  33856
#define FB_MUTAB  34880
#define FB_ZERO_N 33856

static __device__ __forceinline__ short f2bf(float f) {
    union { float f; unsigned u; } v; v.f = f;
    unsigned r = v.u + 0x7FFFu + ((v.u >> 16) & 1u);   // RNE
    return (short)(r >> 16);
}
static __device__ __forceinline__ float bits2f(unsigned u) {
    union { unsigned u; float f; } v; v.u = u; return v.f;
}

__global__ __launch_bounds__(256) void zero_kernel(float* __restrict__ p, int n) {
    int i = blockIdx.x * 256 + threadIdx.x;
    if (i < n) p[i] = 0.0f;
}

// Per-bin prep: biased vnorm, munorm, bf16 codebooks (v, -2v), bf16 W_enc^T /
// W_dec tables. Zero-inits redfin done counter.
__global__ __launch_bounds__(64) void vq_prep(
    const float* __restrict__ vectors, const float* __restrict__ W_enc,
    const float* __restrict__ W_dec, const float* __restrict__ b_dec,
    float* __restrict__ ws)
{
    const int j = blockIdx.x;
    const int t = threadIdx.x;
    float* vnormb = ws + WS_VNORMB;
    float* munorm = ws + WS_MUNORM;
    short* vbf  = (short*)(ws + WS_VBF);
    short* vbf2 = (short*)(ws + WS_VBF2);
    short* wencT = (short*)(ws + WS_WENCT);
    short* wdecb = (short*)(ws + WS_WDECB);

    if (j == 0 && t == 2) ws[WS_FINS + 2] = 0.0f;      // redfin done counter
    if (j == 0) {                                      // W_enc^T bf16: [c][k]
        #pragma unroll
        for (int c = 0; c < DZ; ++c)
            wencT[c * DX + t] = f2bf(W_enc[t * DZ + c]);
    }
    if (j == 1) {                                      // W_dec bf16: [c][d]
        #pragma unroll
        for (int c = 0; c < DZ; ++c)
            wdecb[c * DX + t] = f2bf(W_dec[c * DX + t]);
    }

    __shared__ float v[DZ];
    if (t < DZ) {
        float vv = vectors[j * DZ + t];
        v[t] = vv;
        vbf[j * DZ + t]  = f2bf(vv);
        vbf2[j * DZ + t] = f2bf(-2.0f * vv);
    }
    __syncthreads();
    float m = b_dec[t];
    #pragma unroll
    for (int k = 0; k < DZ; ++k) m = fmaf(v[k], W_dec[k * DX + t], m);
    float ms = m * m;
    #pragma unroll
    for (int off = 32; off > 0; off >>= 1) ms += __shfl_down(ms, off, 64);
    if (t == 0) {
        munorm[j] = ms;
        float s = 0.0f;
        #pragma unroll
        for (int k = 0; k < DZ; ++k) s = fmaf(v[k], v[k], s);
        vnormb[j] = s + BIAS;
    }
}

// ---------- fused MFMA encoder + MFMA argmin + decomposed-recon epilogue ----
// r8/r10-proven structure: 128 rows/block, 2048 blocks, (128,4) -> VGPR 64,
// ZERO spill (r11/r12 lesson: pushing to 6-8 waves/EU spills 20-84MB scratch).
// NO global atomics (r5 lesson).
__global__ __launch_bounds__(ENC_THREADS, 4) void vq_encmin(
    const float* __restrict__ x, const short* __restrict__ wencT,
    const float* __restrict__ b_enc, const short* __restrict__ wdecb,
    const float* __restrict__ b_dec, const short* __restrict__ vbf,
    const short* __restrict__ vbf2, const float* __restrict__ vnormb,
    const float* __restrict__ munorm,
    unsigned* __restrict__ zp, unsigned short* __restrict__ bidx_out,
    float* __restrict__ rpart, float* __restrict__ cpart)
{
    __shared__ __attribute__((aligned(16))) char smem[SMEM_SZ];
    short* xbf = (short*)(smem + SMEM_XBF);
    short* zbf = (short*)(smem + SMEM_ZBF);
    short* ybf = (short*)(smem + SMEM_YBF);
    unsigned* skey = (unsigned*)(smem + SMEM_SKEY);

    const int t = threadIdx.x;
    const int r = blockIdx.x * ENC_THREADS + t;

    // ---- A: coalesced stage of x -> bf16 LDS ----
    const float4* xsrc = (const float4*)(x + (size_t)blockIdx.x * ENC_THREADS * DX);
    #pragma unroll
    for (int i = 0; i < 16; ++i) {
        float4 v = xsrc[i * ENC_THREADS + t];
        unsigned a0 = __builtin_bit_cast(unsigned, v.x) + 0x8000u;
        unsigned a1 = __builtin_bit_cast(unsigned, v.y) + 0x8000u;
        unsigned a2 = __builtin_bit_cast(unsigned, v.z) + 0x8000u;
        unsigned a3 = __builtin_bit_cast(unsigned, v.w) + 0x8000u;
        uint2 pv;
        pv.x = __builtin_amdgcn_perm(a1, a0, 0x07060302u);
        pv.y = __builtin_amdgcn_perm(a3, a2, 0x07060302u);
        const int e = i * ENC_THREADS + t;
        *(uint2*)&xbf[(e >> 4) * XSTR + (e & 15) * 4] = pv;
    }
    __syncthreads();

    // ---- A2: per-row xnorm and x·b_dec from own LDS row ----
    float xnorm = 0.0f, xb = 0.0f;
    #pragma unroll
    for (int i = 0; i < 16; ++i) {
        uint2 q = *(const uint2*)&xbf[t * XSTR + i * 4];
        const float4 bd = ((const float4*)b_dec)[i];
        float f0 = bits2f(q.x << 16), f1 = bits2f(q.x & 0xFFFF0000u);
        float f2 = bits2f(q.y << 16), f3 = bits2f(q.y & 0xFFFF0000u);
        xnorm = fmaf(f0, f0, xnorm); xnorm = fmaf(f1, f1, xnorm);
        xnorm = fmaf(f2, f2, xnorm); xnorm = fmaf(f3, f3, xnorm);
        xb = fmaf(f0, bd.x, xb); xb = fmaf(f1, bd.y, xb);
        xb = fmaf(f2, bd.z, xb); xb = fmaf(f3, bd.w, xb);
    }

    // ---- B: z and y via MFMA ----
    const int w = t >> 6, l = t & 63, lm = l & 15, lq4 = l >> 4;
    shortx8 we[2][2], wd[2][2];
    #pragma unroll
    for (int ct = 0; ct < 2; ++ct)
        #pragma unroll
        for (int kk = 0; kk < 2; ++kk) {
            we[ct][kk] = *(const shortx8*)&wencT[(ct * 16 + lm) * DX + kk * 32 + lq4 * 8];
            wd[ct][kk] = *(const shortx8*)&wdecb[(ct * 16 + lm) * DX + kk * 32 + lq4 * 8];
        }
    const float be0 = b_enc[lm], be1 = b_enc[16 + lm];

    unsigned zpkv[16], ypkv[16];   // packed bf16 pairs (ct0 | ct1<<16)
    #pragma unroll
    for (int rt = 0; rt < 4; ++rt) {
        const int arow = (w * 64 + rt * 16 + lm) * XSTR;
        union { uint2 q[2]; shortx8 s; } a0u, a1u;
        a0u.q[0] = *(const uint2*)&xbf[arow + lq4 * 8];
        a0u.q[1] = *(const uint2*)&xbf[arow + lq4 * 8 + 4];
        a1u.q[0] = *(const uint2*)&xbf[arow + 32 + lq4 * 8];
        a1u.q[1] = *(const uint2*)&xbf[arow + 32 + lq4 * 8 + 4];

        floatx4 z0 = {be0, be0, be0, be0}, z1 = {be1, be1, be1, be1};
        z0 = __builtin_amdgcn_mfma_f32_16x16x32_bf16(a0u.s, we[0][0], z0, 0, 0, 0);
        z0 = __builtin_amdgcn_mfma_f32_16x16x32_bf16(a1u.s, we[0][1], z0, 0, 0, 0);
        z1 = __builtin_amdgcn_mfma_f32_16x16x32_bf16(a0u.s, we[1][0], z1, 0, 0, 0);
        z1 = __builtin_amdgcn_mfma_f32_16x16x32_bf16(a1u.s, we[1][1], z1, 0, 0, 0);
        floatx4 y0 = {0.f, 0.f, 0.f, 0.f}, y1 = {0.f, 0.f, 0.f, 0.f};
        y0 = __builtin_amdgcn_mfma_f32_16x16x32_bf16(a0u.s, wd[0][0], y0, 0, 0, 0);
        y0 = __builtin_amdgcn_mfma_f32_16x16x32_bf16(a1u.s, wd[0][1], y0, 0, 0, 0);
        y1 = __builtin_amdgcn_mfma_f32_16x16x32_bf16(a0u.s, wd[1][0], y1, 0, 0, 0);
        y1 = __builtin_amdgcn_mfma_f32_16x16x32_bf16(a1u.s, wd[1][1], y1, 0, 0, 0);

        #pragma unroll
        for (int reg = 0; reg < 4; ++reg) {
            unsigned zl = __builtin_bit_cast(unsigned, z0[reg]) + 0x8000u;
            unsigned zh = __builtin_bit_cast(unsigned, z1[reg]) + 0x8000u;
            zpkv[rt * 4 + reg] = __builtin_amdgcn_perm(zh, zl, 0x07060302u);
            unsigned yl = __builtin_bit_cast(unsigned, y0[reg]) + 0x8000u;
            unsigned yh = __builtin_bit_cast(unsigned, y1[reg]) + 0x8000u;
            ypkv[rt * 4 + reg] = __builtin_amdgcn_perm(yh, yl, 0x07060302u);
        }
    }
    __syncthreads();   // all xbf reads (A2 + B) complete; region reused

    // ---- B2: scatter z,y bf16 into zbf/ybf ----
    #pragma unroll
    for (int k = 0; k < 16; ++k) {
        const int row = w * 64 + (k >> 2) * 16 + lq4 * 4 + (k & 3);
        zbf[row * ZSTR + lm]      = (short)(zpkv[k] & 0xFFFFu);
        zbf[row * ZSTR + 16 + lm] = (short)(zpkv[k] >> 16);
        ybf[row * YSTR + lm]      = (short)(ypkv[k] & 0xFFFFu);
        ybf[row * YSTR + 16 + lm] = (short)(ypkv[k] >> 16);
    }
    __syncthreads();

    // ---- C: MFMA argmin over 1024 codes ----
    shortx8 afrag[4];
    #pragma unroll
    for (int rt = 0; rt < 4; ++rt)
        afrag[rt] = *(const shortx8*)&zbf[(w * 64 + rt * 16 + lm) * ZSTR + lq4 * 8];

    unsigned key[16];
    #pragma unroll
    for (int k = 0; k < 16; ++k) key[k] = 0xFFFFFFFFu;

    #pragma unroll 8
    for (int jt = 0; jt < 64; ++jt) {
        const int jbase = jt * 16 + lm;
        const shortx8 bfrag = *(const shortx8*)&vbf2[(size_t)jbase * DZ + lq4 * 8];
        const float vn = vnormb[jbase];
        floatx4 cin = {vn, vn, vn, vn};
        #pragma unroll
        for (int rt = 0; rt < 4; ++rt) {
            floatx4 acc = __builtin_amdgcn_mfma_f32_16x16x32_bf16(
                afrag[rt], bfrag, cin, 0, 0, 0);
            #pragma unroll
            for (int reg = 0; reg < 4; ++reg) {
                unsigned u = __builtin_bit_cast(unsigned, acc[reg]);
                unsigned pk = (u & 0xFFFFFC00u) | (unsigned)jbase;
                int k = rt * 4 + reg;
                key[k] = key[k] < pk ? key[k] : pk;
            }
        }
    }

    // cross-lane min over the 16 columns (lm bits); ties -> smaller j
    #pragma unroll
    for (int k = 0; k < 16; ++k) {
        unsigned kv = key[k];
        #pragma unroll
        for (int m = 1; m <= 8; m <<= 1) {
            unsigned ov = __shfl_xor(kv, m, 64);
            kv = ov < kv ? ov : kv;
        }
        if (lm == 0)
            skey[w * 64 + (k >> 2) * 16 + lq4 * 4 + (k & 3)] = kv;
    }
    __syncthreads();

    // ---- D: epilogue ----
    const unsigned kr = skey[t];
    const int bsel = (int)(kr & 1023u);
    const float score = bits2f(kr & 0xFFFFFC00u);
    bidx_out[r] = (unsigned short)bsel;

    float znorm = 0.0f;
    #pragma unroll
    for (int i = 0; i < 4; ++i) {
        uint4 q = *(const uint4*)&zbf[t * ZSTR + i * 8];
        zp[(size_t)(4 * i + 0) * N_ROWS + r] = q.x;
        zp[(size_t)(4 * i + 1) * N_ROWS + r] = q.y;
        zp[(size_t)(4 * i + 2) * N_ROWS + r] = q.z;
        zp[(size_t)(4 * i + 3) * N_ROWS + r] = q.w;
        float f0 = bits2f(q.x << 16), f1 = bits2f(q.x & 0xFFFF0000u);
        float f2 = bits2f(q.y << 16), f3 = bits2f(q.y & 0xFFFF0000u);
        float f4 = bits2f(q.z << 16), f5 = bits2f(q.z & 0xFFFF0000u);
        float f6 = bits2f(q.w << 16), f7 = bits2f(q.w & 0xFFFF0000u);
        znorm = fmaf(f0, f0, znorm); znorm = fmaf(f1, f1, znorm);
        znorm = fmaf(f2, f2, znorm); znorm = fmaf(f3, f3, znorm);
        znorm = fmaf(f4, f4, znorm); znorm = fmaf(f5, f5, znorm);
        znorm = fmaf(f6, f6, znorm); znorm = fmaf(f7, f7, znorm);
    }
    float commit = znorm + (score - BIAS);

    float dot = 0.0f;
    #pragma unroll
    for (int i = 0; i < 8; ++i) {
        uint2 yq = *(const uint2*)&ybf[t * YSTR + i * 4];
        uint2 vq = *(const uint2*)&vbf[(size_t)bsel * DZ + i * 4];
        dot = fmaf(bits2f(yq.x << 16), bits2f(vq.x << 16), dot);
        dot = fmaf(bits2f(yq.x & 0xFFFF0000u), bits2f(vq.x & 0xFFFF0000u), dot);
        dot = fmaf(bits2f(yq.y << 16), bits2f(vq.y << 16), dot);
        dot = fmaf(bits2f(yq.y & 0xFFFF0000u), bits2f(vq.y & 0xFFFF0000u), dot);
    }
    float rs = xnorm - 2.0f * (dot + xb) + munorm[bsel];

    #pragma unroll
    for (int off = 32; off > 0; off >>= 1) {
        rs     += __shfl_down(rs, off, 64);
        commit += __shfl_down(commit, off, 64);
    }
    if (l == 0) {                       // plain stores, NO atomics
        rpart[blockIdx.x * 2 + w] = rs;
        cpart[blockIdx.x * 2 + w] = commit;
    }
}

// ---------- hist: r8-exact (17 roles x 64 chunks, NATIVE INT LDS atomics) ----
// hipcc emits a CAS loop for fp32 LDS atomicAdd (~4-5 cyc/lane); fixed-point
// ds_add_u32 at scale 2^11 is native. Per-chunk |sum| <= 4096*256*2048 < 2^31.
__global__ __launch_bounds__(256) void vq_hist(
    const unsigned* __restrict__ zp, const unsigned short* __restrict__ bidx,
    float* __restrict__ part)
{
    __shared__ int h[2 * NB];
    const int t = threadIdx.x;
    const int ci    = blockIdx.x % HROLES;
    const int chunk = blockIdx.x / HROLES;

    #pragma unroll
    for (int i = 0; i < 8; ++i) h[t + 256 * i] = 0;
    __syncthreads();

    const int base = chunk * HROWS;
    if (ci < 16) {
        const unsigned* zc = zp + (size_t)ci * N_ROWS;
        #pragma unroll 4
        for (int i = 0; i < HROWS / 256; ++i) {
            int r = base + t + 256 * i;
            unsigned w = zc[r];
            int b = bidx[r];
            atomicAdd(&h[b],      __float2int_rn(bits2f(w << 16) * HSCALE));
            atomicAdd(&h[b + NB], __float2int_rn(bits2f(w & 0xFFFF0000u) * HSCALE));
        }
        __syncthreads();
        float* pp = part + (size_t)chunk * PART_STRIDE + (size_t)(2 * ci) * NB;
        #pragma unroll
        for (int i = 0; i < 8; ++i)
            pp[t + 256 * i] = (float)h[t + 256 * i] * (1.0f / HSCALE);
    } else {
        #pragma unroll 4
        for (int i = 0; i < HROWS / 256; ++i) {
            int r = base + t + 256 * i;
            atomicAdd(&h[bidx[r]], 1);
        }
        __syncthreads();
        float* pp = part + (size_t)chunk * PART_STRIDE + (size_t)32 * NB;
        #pragma unroll
        for (int i = 0; i < 4; ++i) pp[t + 256 * i] = (float)h[t + 256 * i];
    }
}

// ---------- reduce + finalize-SCALAR only (132-block last-block-done) ----------
// 132 blocks is under the ~150-block threshold where threadfence+done-counter
// serialization bites (r9 lesson); the 1024x32 vector update stays in its own
// 128-block dispatch (r6 lesson: never put wide work in a one-block tail).
__global__ __launch_bounds__(256) void vq_redfin(
    const float* __restrict__ part, const float* __restrict__ assignments,
    float* __restrict__ ws, float* __restrict__ out)
{
    const int t = threadIdx.x;
    {
        const int o = blockIdx.x * 256 + t;          // 132 blocks -> 33792 outputs
        float s = 0.0f;
        #pragma unroll 8
        for (int c = 0; c < HCHUNKS; ++c)
            s += part[(size_t)c * PART_STRIDE + o];
        (ws + WS_SUMZC)[o] = s;                      // sumzc + counts contiguous
    }
    __shared__ int sdone;
    __threadfence();
    __syncthreads();
    if (t == 0) {
        unsigned old = atomicAdd((unsigned*)ws + WS_FINS + 2, 1u);
        sdone = ((old % (unsigned)RF_BLOCKS) == (unsigned)(RF_BLOCKS - 1)) ? 1 : 0;
    }
    __syncthreads();
    if (!sdone) return;
    __threadfence();

    __shared__ float h[2048];
    __shared__ float sred[4], cred[4];
    __shared__ int s_mx;
    const float* counts = ws + WS_COUNTS;

    {
        const float* rp = ws + WS_RPART;
        const float* cp = ws + WS_CPART;
        float rsum = 0.0f, csum = 0.0f;
        #pragma unroll
        for (int i = 0; i < 16; ++i) {               // 4096 / 256 = 16 each
            rsum += rp[t + 256 * i];
            csum += cp[t + 256 * i];
        }
        #pragma unroll
        for (int off = 32; off > 0; off >>= 1) {
            rsum += __shfl_down(rsum, off, 64);
            csum += __shfl_down(csum, off, 64);
        }
        if ((t & 63) == 0) { sred[t >> 6] = rsum; cred[t >> 6] = csum; }
    }

    float* af           = h;
    unsigned char* dd   = (unsigned char*)(h + 1024);
    int*   tsum         = (int*)(h + 1280);
    float* rv           = h + 1536;
    int*   ri           = (int*)(h + 1792);

    float cnt[4]; int dloc[4];
    float bestv = -1.0f; int besti = 0;
    #pragma unroll
    for (int u = 0; u < 4; ++u) {
        int b = 4 * t + u;
        float c = counts[b]; cnt[u] = c;
        float ba = c / NBF;
        float ae = 0.99f * assignments[b] + 0.01f * ba;
        af[b] = ae;
        int d = (ae * NBF < MIN_ASSIGN) ? 1 : 0;
        dd[b] = (unsigned char)d; dloc[u] = d;
        if (ba > bestv) { bestv = ba; besti = b; }
    }
    rv[t] = bestv; ri[t] = besti;
    __syncthreads();
    for (int s = 128; s > 0; s >>= 1) {
        if (t < s) {
            float ov = rv[t + s]; int oi = ri[t + s];
            if (ov > rv[t] || (ov == rv[t] && oi < ri[t])) { rv[t] = ov; ri[t] = oi; }
        }
        __syncthreads();
    }
    if (t == 0) s_mx = ri[0];
    __syncthreads();
    const int mx = s_mx;
    const float a0mx = af[mx];
    const int na_mx = dd[mx];

    tsum[t] = dloc[0] + dloc[1] + dloc[2] + dloc[3];
    __syncthreads();
    for (int off = 1; off < 256; off <<= 1) {
        int v2 = (t + off < 256) ? tsum[t + off] : 0;
        __syncthreads();
        tsum[t] += v2;
        __syncthreads();
    }
    const int K = tsum[0];
    const int Snext = (t < 255) ? tsum[t + 1] : 0;
    int suf[4];
    suf[3] = dloc[3]; suf[2] = dloc[2] + suf[3];
    suf[1] = dloc[1] + suf[2]; suf[0] = dloc[0] + suf[1];

    #pragma unroll
    for (int u = 0; u < 4; ++u) {
        int b = 4 * t + u;
        float av = af[b];
        int rank = suf[u] + Snext;
        int isd = dd[b];
        if (isd) av = ldexpf(a0mx, -rank);
        if (b == mx && K > 0) av = ldexpf(a0mx, -K);
        out[1 + NB * DZ + b] = av;
        ws[WS_FINS + 64 + b] = (float)isd;     // dead flag for vq_fin_vec
    }
    if (t == 0) {
        ((int*)ws)[WS_FINS] = mx;
        ws[WS_FINS + 1] = (float)na_mx;
        float rtot = sred[0] + sred[1] + sred[2] + sred[3];
        float ctot = cred[0] + cred[1] + cred[2] + cred[3];
        float recon = 0.5f * (rtot / NBF) + 32.0f * 1.8378770664093453f;
        float commit = ctot / (NBF * (float)DZ);
        out[0] = recon + 0.25f * commit;
    }
}

// ---------- finalize (vector part): 1024 bins x 32 comps, fully parallel ----------
__global__ __launch_bounds__(256) void vq_fin_vec(
    const float* __restrict__ vectors, const float* __restrict__ noise,
    const float* __restrict__ ws, float* __restrict__ out)
{
    const int idx = blockIdx.x * 256 + threadIdx.x;   // 128 blocks = 32768
    const int b = idx >> 5, c = idx & 31;
    const int mx = ((const int*)ws)[WS_FINS];
    const float na_mx = ws[WS_FINS + 1];
    const float isd = ws[WS_FINS + 64 + b];
    const float cnt = (ws + WS_COUNTS)[b];
    const float* sumzc = ws + WS_SUMZC;

    float v2 = vectors[b * DZ + c];
    if (isd != 0.0f) {
        const float mxn = (b < mx) ? na_mx : 0.0f;
        v2 = vectors[mx * DZ + c] + mxn * noise[mx * DZ + c] + noise[b * DZ + c];
    }
    float mean = (cnt == 0.0f) ? v2 : (sumzc[(size_t)c * NB + b] / cnt);
    out[1 + b * DZ + c] = 0.99f * v2 + 0.01f * mean;
}

// ---------- fallback (round-1) path, used only if ws is too small ----------
__global__ __launch_bounds__(64) void vq_prep_fb(
    const float* __restrict__ vectors, const float* __restrict__ W_dec,
    const float* __restrict__ b_dec, float* __restrict__ vnorm,
    float* __restrict__ mu_table)
{
    const int j = blockIdx.x;
    const int t = threadIdx.x;
    __shared__ float v[DZ];
    if (t < DZ) v[t] = vectors[j * DZ + t];
    __syncthreads();
    float m = b_dec[t];
    #pragma unroll
    for (int k = 0; k < DZ; ++k) m = fmaf(v[k], W_dec[k * DX + t], m);
    mu_table[(size_t)j * DX + t] = m;
    if (t == 0) {
        float s = 0.0f;
        #pragma unroll
        for (int k = 0; k < DZ; ++k) s = fmaf(v[k], v[k], s);
        vnorm[j] = s;
    }
}

__global__ __launch_bounds__(256) void vq_main_atomic(
    const float* __restrict__ x, const float* __restrict__ W_enc,
    const float* __restrict__ b_enc, const float* __restrict__ vectors,
    const float* __restrict__ vnorm, const float* __restrict__ mu_table,
    float* __restrict__ counts, float* __restrict__ sum_z,
    float* __restrict__ recon_acc, float* __restrict__ commit_acc)
{
    const int r = blockIdx.x * 256 + threadIdx.x;
    float xr[DX];
    const float4* xp = reinterpret_cast<const float4*>(x + (size_t)r * DX);
    #pragma unroll
    for (int i = 0; i < DX / 4; ++i) {
        float4 v = xp[i];
        xr[4 * i + 0] = v.x; xr[4 * i + 1] = v.y;
        xr[4 * i + 2] = v.z; xr[4 * i + 3] = v.w;
    }
    float z[DZ];
    #pragma unroll
    for (int c = 0; c < DZ; ++c) z[c] = b_enc[c];
    #pragma unroll
    for (int k = 0; k < DX; ++k) {
        float xk = xr[k];
        #pragma unroll
        for (int c = 0; c < DZ; ++c) z[c] = fmaf(xk, W_enc[k * DZ + c], z[c]);
    }
    float znorm = 0.0f;
    #pragma unroll
    for (int c = 0; c < DZ; ++c) znorm = fmaf(z[c], z[c], znorm);
    float zm2[DZ];
    #pragma unroll
    for (int c = 0; c < DZ; ++c) zm2[c] = -2.0f * z[c];

    float best = 3.4e38f;
    int bi = 0;
    for (int j = 0; j < NB; ++j) {
        const float* vj = vectors + j * DZ;
        float s0 = vnorm[j], s1 = 0.0f, s2 = 0.0f, s3 = 0.0f;
        #pragma unroll
        for (int c = 0; c < DZ; c += 4) {
            s0 = fmaf(zm2[c + 0], vj[c + 0], s0);
            s1 = fmaf(zm2[c + 1], vj[c + 1], s1);
            s2 = fmaf(zm2[c + 2], vj[c + 2], s2);
            s3 = fmaf(zm2[c + 3], vj[c + 3], s3);
        }
        float s = (s0 + s1) + (s2 + s3);
        if (s < best) { best = s; bi = j; }
    }
    float commit_row = znorm + best;

    float rs = 0.0f;
    const float4* mup = reinterpret_cast<const float4*>(mu_table + (size_t)bi * DX);
    #pragma unroll
    for (int i = 0; i < DX / 4; ++i) {
        float4 m = mup[i];
        float d0 = xr[4 * i + 0] - m.x; rs = fmaf(d0, d0, rs);
        float d1 = xr[4 * i + 1] - m.y; rs = fmaf(d1, d1, rs);
        float d2 = xr[4 * i + 2] - m.z; rs = fmaf(d2, d2, rs);
        float d3 = xr[4 * i + 3] - m.w; rs = fmaf(d3, d3, rs);
    }
    atomicAdd(&counts[bi], 1.0f);
    #pragma unroll
    for (int c = 0; c < DZ; ++c)
        atomicAdd(&sum_z[(size_t)bi * DZ + c], -0.5f * zm2[c]);
    #pragma unroll
    for (int off = 32; off > 0; off >>= 1) {
        rs += __shfl_down(rs, off, 64);
        commit_row += __shfl_down(commit_row, off, 64);
    }
    if ((threadIdx.x & 63) == 0) {
        atomicAdd(recon_acc, rs);
        atomicAdd(commit_acc, commit_row);
    }
}

__global__ __launch_bounds__(1024) void vq_finalize_fb(
    const float* __restrict__ vectors, const float* __restrict__ assignments,
    const float* __restrict__ noise, const float* __restrict__ counts,
    const float* __restrict__ sum_z, const float* __restrict__ recon_acc,
    const float* __restrict__ commit_acc, float* __restrict__ out)
{
    __shared__ float a[NB];
    __shared__ unsigned char na[NB];
    __shared__ float rv[NB];
    __shared__ int ri[NB];
    __shared__ int s_max_idx;
    const int t = threadIdx.x;

    const float cnt = counts[t];
    const float ba = cnt / NBF;
    const float ae = 0.99f * assignments[t] + 0.01f * ba;
    a[t] = ae;
    na[t] = (ae * NBF < MIN_ASSIGN) ? 1 : 0;
    rv[t] = ba; ri[t] = t;
    __syncthreads();
    for (int s = NB / 2; s > 0; s >>= 1) {
        if (t < s) {
            float ov = rv[t + s]; int oi = ri[t + s];
            if (ov > rv[t] || (ov == rv[t] && oi < ri[t])) { rv[t] = ov; ri[t] = oi; }
        }
        __syncthreads();
    }
    if (t == 0) s_max_idx = ri[0];
    __syncthreads();
    const int mx = s_max_idx;
    if (t == 0) {
        for (int i = NB - 1; i >= 0; --i) {
            if (na[i]) { float v = 0.5f * a[mx]; a[i] = v; a[mx] = v; }
        }
    }
    __syncthreads();
    out[1 + NB * DZ + t] = a[t];
    const bool dead = (na[t] != 0);
    #pragma unroll
    for (int c = 0; c < DZ; ++c) {
        float v2 = dead ? (vectors[mx * DZ + c] + noise[t * DZ + c])
                        : vectors[t * DZ + c];
        float mean = (cnt == 0.0f) ? v2 : (sum_z[(size_t)t * DZ + c] / cnt);
        out[1 + t * DZ + c] = 0.99f * v2 + 0.01f * mean;
    }
    if (t == 0) {
        float recon = 0.5f * (recon_acc[0] / NBF) + 32.0f * 1.8378770664093453f;
        float commit = commit_acc[0] / (NBF * (float)DZ);
        out[0] = recon + 0.25f * commit;
    }
}

extern "C" void kernel_launch(void* const* d_in, const int* in_sizes, int n_in,
                              void* d_out, int out_size, void* d_ws, size_t ws_size,
                              hipStream_t stream)
{
    const float* x           = (const float*)d_in[0];
    const float* W_enc       = (const float*)d_in[1];
    const float* b_enc       = (const float*)d_in[2];
    const float* vectors     = (const float*)d_in[3];
    const float* W_dec       = (const float*)d_in[4];
    const float* b_dec       = (const float*)d_in[5];
    const float* assignments = (const float*)d_in[6];
    const float* noise       = (const float*)d_in[7];
    float* out = (float*)d_out;
    float* ws  = (float*)d_ws;

    if (ws_size >= (size_t)WS_TOTAL * sizeof(float)) {
        vq_prep<<<NB, 64, 0, stream>>>(vectors, W_enc, W_dec, b_dec, ws);
        vq_encmin<<<ENC_BLOCKS, ENC_THREADS, 0, stream>>>(x,
            (const short*)(ws + WS_WENCT), b_enc,
            (const short*)(ws + WS_WDECB), b_dec,
            (const short*)(ws + WS_VBF), (const short*)(ws + WS_VBF2),
            ws + WS_VNORMB, ws + WS_MUNORM,
            (unsigned*)(ws + WS_ZP), (unsigned short*)(ws + WS_BIDX),
            ws + WS_RPART, ws + WS_CPART);
        vq_hist<<<HBLOCKS, 256, 0, stream>>>(
            (const unsigned*)(ws + WS_ZP),
            (const unsigned short*)(ws + WS_BIDX),
            ws + WS_PART);
        vq_redfin<<<RF_BLOCKS, 256, 0, stream>>>(
            ws + WS_PART, assignments, ws, out);
        vq_fin_vec<<<(NB * DZ) / 256, 256, 0, stream>>>(vectors, noise, ws, out);
    } else {
        zero_kernel<<<(FB_ZERO_N + 255) / 256, 256, 0, stream>>>(ws, FB_ZERO_N);
        vq_prep_fb<<<NB, 64, 0, stream>>>(vectors, W_dec, b_dec,
            ws + FB_VNORM, ws + FB_MUTAB);
        vq_main_atomic<<<N_ROWS / 256, 256, 0, stream>>>(x, W_enc, b_enc, vectors,
            ws + FB_VNORM, ws + FB_MUTAB, ws + FB_COUNTS, ws + FB_SUMZ,
            ws + FB_RECON, ws + FB_COMMIT);
        vq_finalize_fb<<<1, NB, 0, stream>>>(vectors, assignments, noise,
            ws + FB_COUNTS, ws + FB_SUMZ, ws + FB_RECON, ws + FB_COMMIT, out);
    }
}